// Round 1
// baseline (21891.530 us; speedup 1.0000x reference)
//
#include <hip/hip_runtime.h>
#include <stdint.h>

// Problem constants (MCB_42949672960828)
#define Bsz  1024
#define D0n  2048
#define D1n  2048
#define MMn  16000
#define OUTn 3000

typedef __attribute__((ext_vector_type(8))) short bf16x8;
typedef __attribute__((ext_vector_type(4))) float f32x4;

__device__ __forceinline__ unsigned short f2bf(float f) {
    union { float fv; uint32_t u; } v; v.fv = f;
    return (unsigned short)((v.u + 0x7fffu + ((v.u >> 16) & 1u)) >> 16);
}

// ---------------------------------------------------------------------------
// Kernel 1: per-batch pairwise count-sketch circular convolution in LDS.
// z[b,m] = sum_{j,k} c0[b,j]*c1[b,k] * [(h0[j]+h1[k]) mod MM == m]
// One block per batch row; z accumulated with LDS float atomics; output bf16.
// ---------------------------------------------------------------------------
__global__ __launch_bounds__(256) void conv_kernel(
    const float* __restrict__ x0, const float* __restrict__ x1,
    const int* __restrict__ h0, const int* __restrict__ h1,
    const int* __restrict__ s0, const int* __restrict__ s1,
    unsigned short* __restrict__ zb)  // [Bsz, MMn] bf16
{
    __shared__ float zs[MMn];      // 64000 B
    __shared__ float c1s[128];     // chunked staging keeps static LDS <= 64 KiB
    __shared__ int   h1s[128];

    const int b = blockIdx.x;
    const int tid = threadIdx.x;

    for (int i = tid; i < MMn; i += 256) zs[i] = 0.f;

    // per-thread register strip of the j dimension (8 = 2048/256)
    float c0r[8]; int h0r[8];
#pragma unroll
    for (int i = 0; i < 8; i++) {
        int j = tid + 256 * i;
        c0r[i] = x0[(size_t)b * D0n + j] * (float)(2 * s0[j] - 1);
        h0r[i] = h0[j];
    }

    for (int kb = 0; kb < D1n; kb += 128) {
        __syncthreads();   // also covers zs zero-init on first pass
        if (tid < 128) {
            int k = kb + tid;
            c1s[tid] = x1[(size_t)b * D1n + k] * (float)(2 * s1[k] - 1);
            h1s[tid] = h1[k];
        }
        __syncthreads();
        for (int kk = 0; kk < 128; kk++) {
            const float vk = c1s[kk];   // wave-uniform LDS broadcast
            const int   sk = h1s[kk];
#pragma unroll
            for (int i = 0; i < 8; i++) {
                int m = h0r[i] + sk;
                m -= (m >= MMn) ? MMn : 0;
                atomicAdd(&zs[m], c0r[i] * vk);   // ds_add_f32, no return
            }
        }
    }
    __syncthreads();

    unsigned short* zrow = zb + (size_t)b * MMn;
    for (int i = tid; i < MMn; i += 256) zrow[i] = f2bf(zs[i]);
}

// ---------------------------------------------------------------------------
// Kernel 2: y = ReLU(z @ W^T + bias), bf16 MFMA, fp32 accumulate.
// M=1024 (batch), N=3000 (out), K=16000. Tile 64x128, BK=32, 4 waves,
// wave-tile 32x64 (2x4 MFMA 16x16x32 frags). W converted fp32->bf16 during
// LDS staging (W is read ~once from HBM; L3 absorbs re-reads).
// ---------------------------------------------------------------------------
#define BM 64
#define BN 128
#define BK 32
#define LDK 40   // padded row stride (bf16 elems): 32 + 8 breaks bank strides

__global__ __launch_bounds__(256) void gemm_kernel(
    const unsigned short* __restrict__ Z,   // [Bsz, MMn] bf16
    const float* __restrict__ W,            // [OUTn, MMn] f32
    const float* __restrict__ bias,         // [OUTn]
    float* __restrict__ out)                // [Bsz, OUTn] f32
{
    __shared__ __align__(16) unsigned short As[BM * LDK];   // 5120 B
    __shared__ __align__(16) unsigned short Bs[BN * LDK];   // 10240 B

    const int tid = threadIdx.x;
    const int m0 = blockIdx.y * BM;
    const int n0 = blockIdx.x * BN;
    const int lane = tid & 63;
    const int w  = tid >> 6;
    const int wm = w >> 1;   // 0..1 -> 32-row slab
    const int wn = w & 1;    // 0..1 -> 64-col slab

    // A staging: 256 chunks of 16 B (8 bf16); chunk = tid
    const int ar = tid >> 2, aq = tid & 3;
    const uint4* aSrc = (const uint4*)(Z + (size_t)(m0 + ar) * MMn + aq * 8);
    unsigned short* aDst = As + ar * LDK + aq * 8;

    // B staging: 1024 chunks of float4 (4 f32 -> 4 bf16)
    const float4* bSrc[4];
    unsigned short* bDst[4];
#pragma unroll
    for (int p = 0; p < 4; p++) {
        int ch = tid + 256 * p;
        int r = ch >> 3, q = ch & 7;
        int rw = n0 + r; if (rw > OUTn - 1) rw = OUTn - 1;  // clamp tail tile
        bSrc[p] = (const float4*)(W + (size_t)rw * MMn + q * 4);
        bDst[p] = Bs + r * LDK + q * 4;
    }

    // MFMA fragment read addresses (lane L: m/n = L&15, k = (L>>4)*8 + j)
    const int qh = lane >> 4;
    const int lr = lane & 15;
    const unsigned short* aRd[2];
    const unsigned short* bRd[4];
#pragma unroll
    for (int i = 0; i < 2; i++) aRd[i] = As + (wm * 32 + i * 16 + lr) * LDK + qh * 8;
#pragma unroll
    for (int j = 0; j < 4; j++) bRd[j] = Bs + (wn * 64 + j * 16 + lr) * LDK + qh * 8;

    f32x4 acc[2][4];
#pragma unroll
    for (int i = 0; i < 2; i++)
#pragma unroll
        for (int j = 0; j < 4; j++)
            acc[i][j] = (f32x4){0.f, 0.f, 0.f, 0.f};

    for (int k0 = 0; k0 < MMn; k0 += BK) {
        uint4 av = aSrc[k0 >> 3];
        float4 bv[4];
#pragma unroll
        for (int p = 0; p < 4; p++) bv[p] = bSrc[p][k0 >> 2];

        __syncthreads();   // prev iter's ds_reads complete before overwrite
        *(uint4*)aDst = av;
#pragma unroll
        for (int p = 0; p < 4; p++) {
            uint2 pk;
            pk.x = (uint32_t)f2bf(bv[p].x) | ((uint32_t)f2bf(bv[p].y) << 16);
            pk.y = (uint32_t)f2bf(bv[p].z) | ((uint32_t)f2bf(bv[p].w) << 16);
            *(uint2*)bDst[p] = pk;
        }
        __syncthreads();

        bf16x8 af[2], bfr[4];
#pragma unroll
        for (int i = 0; i < 2; i++) af[i] = *(const bf16x8*)aRd[i];
#pragma unroll
        for (int j = 0; j < 4; j++) bfr[j] = *(const bf16x8*)bRd[j];
#pragma unroll
        for (int i = 0; i < 2; i++)
#pragma unroll
            for (int j = 0; j < 4; j++)
                acc[i][j] = __builtin_amdgcn_mfma_f32_16x16x32_bf16(
                    af[i], bfr[j], acc[i][j], 0, 0, 0);
    }

    // Epilogue: bias + ReLU; D frag: row(m) = (lane>>4)*4 + reg, col(n) = lane&15
#pragma unroll
    for (int j = 0; j < 4; j++) {
        int n = n0 + wn * 64 + j * 16 + lr;
        if (n < OUTn) {
            float bvb = bias[n];
#pragma unroll
            for (int i = 0; i < 2; i++) {
                int mb = m0 + wm * 32 + i * 16 + qh * 4;
#pragma unroll
                for (int reg = 0; reg < 4; reg++) {
                    float v = acc[i][j][reg] + bvb;
                    out[(size_t)(mb + reg) * OUTn + n] = v > 0.f ? v : 0.f;
                }
            }
        }
    }
}

extern "C" void kernel_launch(void* const* d_in, const int* in_sizes, int n_in,
                              void* d_out, int out_size, void* d_ws, size_t ws_size,
                              hipStream_t stream) {
    const float* x0 = (const float*)d_in[0];
    const float* x1 = (const float*)d_in[1];
    const int*   h0 = (const int*)d_in[2];
    const int*   h1 = (const int*)d_in[3];
    const int*   s0 = (const int*)d_in[4];
    const int*   s1 = (const int*)d_in[5];
    const float* W  = (const float*)d_in[6];
    const float* bb = (const float*)d_in[7];
    float* out = (float*)d_out;

    unsigned short* zb = (unsigned short*)d_ws;  // [1024, 16000] bf16 = 32.8 MB

    conv_kernel<<<Bsz, 256, 0, stream>>>(x0, x1, h0, h1, s0, s1, zb);

    dim3 grid((OUTn + BN - 1) / BN, Bsz / BM);   // 24 x 16 = 384 blocks
    gemm_kernel<<<grid, 256, 0, stream>>>(zb, W, bb, out);
}

// Round 2
// 950.146 us; speedup vs baseline: 23.0402x; 23.0402x over previous
//
#include <hip/hip_runtime.h>
#include <stdint.h>

// Problem constants (MCB_42949672960828)
#define Bsz  1024
#define D0n  2048
#define D1n  2048
#define MMn  16000
#define OUTn 3000
#define FBLK 512   // threads for FFT kernel

typedef __attribute__((ext_vector_type(8))) short bf16x8;
typedef __attribute__((ext_vector_type(4))) float f32x4;

__device__ __forceinline__ unsigned short f2bf(float f) {
    union { float fv; uint32_t u; } v; v.fv = f;
    return (unsigned short)((v.u + 0x7fffu + ((v.u >> 16) & 1u)) >> 16);
}

__device__ __forceinline__ float2 operator+(float2 a, float2 b){ return make_float2(a.x+b.x, a.y+b.y); }
__device__ __forceinline__ float2 operator-(float2 a, float2 b){ return make_float2(a.x-b.x, a.y-b.y); }
__device__ __forceinline__ float2 operator*(float s, float2 a){ return make_float2(s*a.x, s*a.y); }
__device__ __forceinline__ float2 cmul(float2 a, float2 b){ return make_float2(a.x*b.x - a.y*b.y, a.x*b.y + a.y*b.x); }

// ---------------------------------------------------------------------------
// Mixed-radix in-place FFT, N = 16000 = 4*4*4*2*5*5*5.
// Forward DIF: natural input -> digit-scrambled spectrum.
// Inverse: exact algebraic inverse of each stage, reverse order:
//          scrambled input -> natural output (unscaled by N).
// ---------------------------------------------------------------------------

// radix-r DFT butterfly; sgn = -1 forward (w = e^{-2pi i/r}), +1 inverse
template<int R>
__device__ __forceinline__ void dft_r(const float2* a, float2* A, float sgn) {
    if constexpr (R == 2) {
        A[0] = a[0] + a[1];
        A[1] = a[0] - a[1];
    } else if constexpr (R == 4) {
        float2 t0 = a[0] + a[2], t1 = a[0] - a[2];
        float2 t2 = a[1] + a[3], t3 = a[1] - a[3];
        float2 it3 = make_float2(-sgn * t3.y, sgn * t3.x);  // sgn*i*t3
        A[0] = t0 + t2;  A[2] = t0 - t2;
        A[1] = t1 + it3; A[3] = t1 - it3;
    } else {  // R == 5
        const float c1 = 0.30901699f,  s1 = 0.95105652f;
        const float c2 = -0.80901699f, s2 = 0.58778525f;
        float2 t1 = a[1] + a[4], t3 = a[1] - a[4];
        float2 t2 = a[2] + a[3], t4 = a[2] - a[3];
        float2 b1 = a[0] + c1 * t1 + c2 * t2;
        float2 b2 = a[0] + c2 * t1 + c1 * t2;
        float2 u  = s1 * t3 + s2 * t4;
        float2 v  = s2 * t3 - s1 * t4;
        float2 iu = make_float2(-sgn * u.y, sgn * u.x);  // sgn*i*u
        float2 iv = make_float2(-sgn * v.y, sgn * v.x);
        A[0] = a[0] + t1 + t2;
        A[1] = b1 + iu;  A[4] = b1 - iu;
        A[2] = b2 + iv;  A[3] = b2 - iv;
    }
}

// One in-place stage. NC = current transform length, M = NC/R butterbfly span.
// Forward: gather at base+M*t, DFT, twiddle e^{-2pi i p u/NC}, scatter base+M*u.
// Inverse: gather at base+M*u, un-twiddle e^{+2pi i p u/NC}, inv-DFT, scatter base+M*t.
template<int NC, int R, bool INV>
__device__ __forceinline__ void fft_stage(float2* X) {
    constexpr int M = NC / R;
    constexpr int NBF = MMn / R;
    constexpr float sgn = INV ? 1.0f : -1.0f;
    for (int e = threadIdx.x; e < NBF; e += FBLK) {
        const int blk = e / M;             // compile-time M -> magic mul
        const int p   = e - blk * M;
        const int base = blk * NC + p;
        float2 a[R];
#pragma unroll
        for (int t = 0; t < R; t++) a[t] = X[base + M * t];
        if constexpr (INV && M > 1) {
#pragma unroll
            for (int u = 1; u < R; u++) {
                float ang = 6.28318530718f * (float)((p * u) % NC) / (float)NC;
                float s, c; __sincosf(ang, &s, &c);
                a[u] = cmul(a[u], make_float2(c, s));
            }
        }
        float2 A[R];
        dft_r<R>(a, A, sgn);
        if constexpr (!INV && M > 1) {
#pragma unroll
            for (int u = 1; u < R; u++) {
                float ang = -6.28318530718f * (float)((p * u) % NC) / (float)NC;
                float s, c; __sincosf(ang, &s, &c);
                A[u] = cmul(A[u], make_float2(c, s));
            }
        }
#pragma unroll
        for (int t = 0; t < R; t++) X[base + M * t] = A[t];
    }
}

// position of natural frequency k in the DIF-scrambled array.
// sigma(p) = d1 + r1*(d2 + r2*(...)), radices (4,4,4,2,5,5,5),
// weights N/(r1..ri) = (4000,1000,250,125,25,5,1)
__device__ __forceinline__ int sigma_inv(int k) {
    int p = 0;
    p += (k & 3) * 4000; k >>= 2;
    p += (k & 3) * 1000; k >>= 2;
    p += (k & 3) * 250;  k >>= 2;
    p += (k & 1) * 125;  k >>= 1;
    p += (k % 5) * 25;   k /= 5;
    p += (k % 5) * 5;    k /= 5;
    p += k;
    return p;
}

// ---------------------------------------------------------------------------
// Kernel 1: per-batch-row count-sketch + circular convolution via packed FFT.
// LDS: 16000 complex f32 = 128000 B (dynamic). One block per row, 512 thr.
// Packs q = p0 + i*p1; one fwd FFT; unpack/multiply via conj symmetry at
// digit-reversed positions; one inverse FFT; z written natural-order as bf16.
// ---------------------------------------------------------------------------
__global__ __launch_bounds__(FBLK) void fft_conv_kernel(
    const float* __restrict__ x0, const float* __restrict__ x1,
    const int* __restrict__ h0, const int* __restrict__ h1,
    const int* __restrict__ s0, const int* __restrict__ s1,
    unsigned short* __restrict__ zb)  // [Bsz, MMn] bf16
{
    extern __shared__ float2 X[];   // MMn complex
    const int b = blockIdx.x;
    const int tid = threadIdx.x;

    for (int i = tid; i < MMn; i += FBLK) X[i] = make_float2(0.f, 0.f);
    __syncthreads();

    // scatter count sketches: p0 -> real, p1 -> imag (few collisions; atomics cheap here)
    for (int j = tid; j < D0n; j += FBLK) {
        float v = x0[(size_t)b * D0n + j] * (float)(2 * s0[j] - 1);
        atomicAdd(&X[h0[j]].x, v);
    }
    for (int j = tid; j < D1n; j += FBLK) {
        float v = x1[(size_t)b * D1n + j] * (float)(2 * s1[j] - 1);
        atomicAdd(&X[h1[j]].y, v);
    }
    __syncthreads();

    // forward FFT (DIF, scrambled output)
    fft_stage<16000,4,false>(X); __syncthreads();
    fft_stage<4000, 4,false>(X); __syncthreads();
    fft_stage<1000, 4,false>(X); __syncthreads();
    fft_stage<250,  2,false>(X); __syncthreads();
    fft_stage<125,  5,false>(X); __syncthreads();
    fft_stage<25,   5,false>(X); __syncthreads();
    fft_stage<5,    5,false>(X); __syncthreads();

    // unpack packed spectra + pointwise product, in scrambled space
    for (int k = tid; k <= MMn / 2; k += FBLK) {
        if (k == 0 || k == MMn / 2) {
            int p = sigma_inv(k);
            float2 Q = X[p];
            X[p] = make_float2(Q.x * Q.y, 0.f);   // F0,F1 real here
        } else {
            int pa = sigma_inv(k), pb = sigma_inv(MMn - k);
            float2 Qa = X[pa], Qb = X[pb];
            float2 F0 = make_float2(0.5f * (Qa.x + Qb.x), 0.5f * (Qa.y - Qb.y));
            float2 dd = make_float2(Qa.x - Qb.x, Qa.y + Qb.y);
            float2 F1 = make_float2(0.5f * dd.y, -0.5f * dd.x);   // dd/(2i)
            float2 H = cmul(F0, F1);
            X[pa] = H;
            X[pb] = make_float2(H.x, -H.y);   // H[N-k] = conj(H[k])
        }
    }
    __syncthreads();

    // inverse FFT (exact stage inverses, reverse order -> natural output)
    fft_stage<5,    5,true>(X); __syncthreads();
    fft_stage<25,   5,true>(X); __syncthreads();
    fft_stage<125,  5,true>(X); __syncthreads();
    fft_stage<250,  2,true>(X); __syncthreads();
    fft_stage<1000, 4,true>(X); __syncthreads();
    fft_stage<4000, 4,true>(X); __syncthreads();
    fft_stage<16000,4,true>(X); __syncthreads();

    const float invN = 1.0f / (float)MMn;
    unsigned short* zrow = zb + (size_t)b * MMn;
    for (int m = tid; m < MMn; m += FBLK) zrow[m] = f2bf(X[m].x * invN);
}

// ---------------------------------------------------------------------------
// Kernel 2: y = ReLU(z @ W^T + bias)  — unchanged from R0 (known correct).
// ---------------------------------------------------------------------------
#define BM 64
#define BN 128
#define BK 32
#define LDK 40

__global__ __launch_bounds__(256) void gemm_kernel(
    const unsigned short* __restrict__ Z,   // [Bsz, MMn] bf16
    const float* __restrict__ W,            // [OUTn, MMn] f32
    const float* __restrict__ bias,         // [OUTn]
    float* __restrict__ out)                // [Bsz, OUTn] f32
{
    __shared__ __align__(16) unsigned short As[BM * LDK];
    __shared__ __align__(16) unsigned short Bs[BN * LDK];

    const int tid = threadIdx.x;
    const int m0 = blockIdx.y * BM;
    const int n0 = blockIdx.x * BN;
    const int lane = tid & 63;
    const int w  = tid >> 6;
    const int wm = w >> 1;
    const int wn = w & 1;

    const int ar = tid >> 2, aq = tid & 3;
    const uint4* aSrc = (const uint4*)(Z + (size_t)(m0 + ar) * MMn + aq * 8);
    unsigned short* aDst = As + ar * LDK + aq * 8;

    const float4* bSrc[4];
    unsigned short* bDst[4];
#pragma unroll
    for (int p = 0; p < 4; p++) {
        int ch = tid + 256 * p;
        int r = ch >> 3, q = ch & 7;
        int rw = n0 + r; if (rw > OUTn - 1) rw = OUTn - 1;
        bSrc[p] = (const float4*)(W + (size_t)rw * MMn + q * 4);
        bDst[p] = Bs + r * LDK + q * 4;
    }

    const int qh = lane >> 4;
    const int lr = lane & 15;
    const unsigned short* aRd[2];
    const unsigned short* bRd[4];
#pragma unroll
    for (int i = 0; i < 2; i++) aRd[i] = As + (wm * 32 + i * 16 + lr) * LDK + qh * 8;
#pragma unroll
    for (int j = 0; j < 4; j++) bRd[j] = Bs + (wn * 64 + j * 16 + lr) * LDK + qh * 8;

    f32x4 acc[2][4];
#pragma unroll
    for (int i = 0; i < 2; i++)
#pragma unroll
        for (int j = 0; j < 4; j++)
            acc[i][j] = (f32x4){0.f, 0.f, 0.f, 0.f};

    for (int k0 = 0; k0 < MMn; k0 += BK) {
        uint4 av = aSrc[k0 >> 3];
        float4 bv[4];
#pragma unroll
        for (int p = 0; p < 4; p++) bv[p] = bSrc[p][k0 >> 2];

        __syncthreads();
        *(uint4*)aDst = av;
#pragma unroll
        for (int p = 0; p < 4; p++) {
            uint2 pk;
            pk.x = (uint32_t)f2bf(bv[p].x) | ((uint32_t)f2bf(bv[p].y) << 16);
            pk.y = (uint32_t)f2bf(bv[p].z) | ((uint32_t)f2bf(bv[p].w) << 16);
            *(uint2*)bDst[p] = pk;
        }
        __syncthreads();

        bf16x8 af[2], bfr[4];
#pragma unroll
        for (int i = 0; i < 2; i++) af[i] = *(const bf16x8*)aRd[i];
#pragma unroll
        for (int j = 0; j < 4; j++) bfr[j] = *(const bf16x8*)bRd[j];
#pragma unroll
        for (int i = 0; i < 2; i++)
#pragma unroll
            for (int j = 0; j < 4; j++)
                acc[i][j] = __builtin_amdgcn_mfma_f32_16x16x32_bf16(
                    af[i], bfr[j], acc[i][j], 0, 0, 0);
    }

#pragma unroll
    for (int j = 0; j < 4; j++) {
        int n = n0 + wn * 64 + j * 16 + lr;
        if (n < OUTn) {
            float bvb = bias[n];
#pragma unroll
            for (int i = 0; i < 2; i++) {
                int mb = m0 + wm * 32 + i * 16 + qh * 4;
#pragma unroll
                for (int reg = 0; reg < 4; reg++) {
                    float v = acc[i][j][reg] + bvb;
                    out[(size_t)(mb + reg) * OUTn + n] = v > 0.f ? v : 0.f;
                }
            }
        }
    }
}

extern "C" void kernel_launch(void* const* d_in, const int* in_sizes, int n_in,
                              void* d_out, int out_size, void* d_ws, size_t ws_size,
                              hipStream_t stream) {
    const float* x0 = (const float*)d_in[0];
    const float* x1 = (const float*)d_in[1];
    const int*   h0 = (const int*)d_in[2];
    const int*   h1 = (const int*)d_in[3];
    const int*   s0 = (const int*)d_in[4];
    const int*   s1 = (const int*)d_in[5];
    const float* W  = (const float*)d_in[6];
    const float* bb = (const float*)d_in[7];
    float* out = (float*)d_out;

    unsigned short* zb = (unsigned short*)d_ws;  // [1024,16000] bf16 = 32.8 MB

    // 128000 B dynamic LDS (>64K default cap) for the 16000-pt complex buffer
    hipFuncSetAttribute((const void*)fft_conv_kernel,
                        hipFuncAttributeMaxDynamicSharedMemorySize, 131072);

    fft_conv_kernel<<<Bsz, FBLK, 128000, stream>>>(x0, x1, h0, h1, s0, s1, zb);

    dim3 grid((OUTn + BN - 1) / BN, Bsz / BM);
    gemm_kernel<<<grid, 256, 0, stream>>>(zb, W, bb, out);
}

// Round 3
// 558.629 us; speedup vs baseline: 39.1880x; 1.7009x over previous
//
#include <hip/hip_runtime.h>
#include <stdint.h>

// Problem constants (MCB_42949672960828)
#define Bsz  1024
#define D0n  2048
#define D1n  2048
#define MMn  16000
#define OUTn 3000
#define FBLK 1024   // threads for FFT kernel (128KB LDS -> 1 block/CU; 16 waves)

typedef __attribute__((ext_vector_type(8))) short bf16x8;
typedef __attribute__((ext_vector_type(4))) float f32x4;

__device__ __forceinline__ unsigned short f2bf(float f) {
    union { float fv; uint32_t u; } v; v.fv = f;
    return (unsigned short)((v.u + 0x7fffu + ((v.u >> 16) & 1u)) >> 16);
}

__device__ __forceinline__ float2 operator+(float2 a, float2 b){ return make_float2(a.x+b.x, a.y+b.y); }
__device__ __forceinline__ float2 operator-(float2 a, float2 b){ return make_float2(a.x-b.x, a.y-b.y); }
__device__ __forceinline__ float2 operator*(float s, float2 a){ return make_float2(s*a.x, s*a.y); }
__device__ __forceinline__ float2 cmul(float2 a, float2 b){ return make_float2(a.x*b.x - a.y*b.y, a.x*b.y + a.y*b.x); }

// async 16B global -> LDS (direct-to-shared DMA)
__device__ __forceinline__ void gll16(const void* g, void* l) {
    __builtin_amdgcn_global_load_lds(
        (const __attribute__((address_space(1))) uint32_t*)g,
        (__attribute__((address_space(3))) uint32_t*)l, 16, 0, 0);
}

// ---------------------------------------------------------------------------
// Twiddle table for N = 16000 = 4*4*4*2*5*5*5 DIF FFT.
// Stage s (NC,R,M): entries (p in [0,M), u in [1,R)): e^{-2pi i (p*u mod NC)/NC}
// offsets: (16000,4):0 len12000 | (4000,4):12000 len3000 | (1000,4):15000
// len750 | (250,2):15750 len125 | (125,5):15875 len100 | (25,5):15975 len20
// ---------------------------------------------------------------------------
#define TWN 15995

__global__ __launch_bounds__(256) void tw_init_kernel(float2* __restrict__ tw) {
    int g = blockIdx.x * 256 + threadIdx.x;
    if (g >= TWN) return;
    int NC, p, u;
    if (g < 12000)      { NC = 16000; int e = g;         p = e / 3; u = e % 3 + 1; }
    else if (g < 15000) { NC = 4000;  int e = g - 12000; p = e / 3; u = e % 3 + 1; }
    else if (g < 15750) { NC = 1000;  int e = g - 15000; p = e / 3; u = e % 3 + 1; }
    else if (g < 15875) { NC = 250;   int e = g - 15750; p = e;     u = 1;         }
    else if (g < 15975) { NC = 125;   int e = g - 15875; p = e / 4; u = e % 4 + 1; }
    else                { NC = 25;    int e = g - 15975; p = e / 4; u = e % 4 + 1; }
    float ang = -6.28318530718f * (float)((p * u) % NC) / (float)NC;
    float s, c; __sincosf(ang, &s, &c);
    tw[g] = make_float2(c, s);
}

// radix-r DFT butterfly; sgn = -1 forward, +1 inverse
template<int R>
__device__ __forceinline__ void dft_r(const float2* a, float2* A, float sgn) {
    if constexpr (R == 2) {
        A[0] = a[0] + a[1];
        A[1] = a[0] - a[1];
    } else if constexpr (R == 4) {
        float2 t0 = a[0] + a[2], t1 = a[0] - a[2];
        float2 t2 = a[1] + a[3], t3 = a[1] - a[3];
        float2 it3 = make_float2(-sgn * t3.y, sgn * t3.x);
        A[0] = t0 + t2;  A[2] = t0 - t2;
        A[1] = t1 + it3; A[3] = t1 - it3;
    } else {  // R == 5
        const float c1 = 0.30901699f,  s1 = 0.95105652f;
        const float c2 = -0.80901699f, s2 = 0.58778525f;
        float2 t1 = a[1] + a[4], t3 = a[1] - a[4];
        float2 t2 = a[2] + a[3], t4 = a[2] - a[3];
        float2 b1 = a[0] + c1 * t1 + c2 * t2;
        float2 b2 = a[0] + c2 * t1 + c1 * t2;
        float2 u  = s1 * t3 + s2 * t4;
        float2 v  = s2 * t3 - s1 * t4;
        float2 iu = make_float2(-sgn * u.y, sgn * u.x);
        float2 iv = make_float2(-sgn * v.y, sgn * v.x);
        A[0] = a[0] + t1 + t2;
        A[1] = b1 + iu;  A[4] = b1 - iu;
        A[2] = b2 + iv;  A[3] = b2 - iv;
    }
}

// In-place stage; twiddles from table (inverse = conjugate).
template<int NC, int R, bool INV>
__device__ __forceinline__ void fft_stage(float2* X, const float2* __restrict__ tw) {
    constexpr int M = NC / R;
    constexpr int NBF = MMn / R;
    constexpr float sgn = INV ? 1.0f : -1.0f;
    for (int e = threadIdx.x; e < NBF; e += FBLK) {
        const int blk = e / M;
        const int p   = e - blk * M;
        const int base = blk * NC + p;
        float2 a[R];
#pragma unroll
        for (int t = 0; t < R; t++) a[t] = X[base + M * t];
        if constexpr (INV && M > 1) {
#pragma unroll
            for (int u = 1; u < R; u++) {
                float2 w = tw[p * (R - 1) + (u - 1)];
                a[u] = cmul(a[u], make_float2(w.x, -w.y));
            }
        }
        float2 A[R];
        dft_r<R>(a, A, sgn);
        if constexpr (!INV && M > 1) {
#pragma unroll
            for (int u = 1; u < R; u++) {
                float2 w = tw[p * (R - 1) + (u - 1)];
                A[u] = cmul(A[u], w);
            }
        }
#pragma unroll
        for (int t = 0; t < R; t++) X[base + M * t] = A[t];
    }
}

// position of natural frequency k in the DIF-scrambled array
__device__ __forceinline__ int sigma_inv(int k) {
    int p = 0;
    p += (k & 3) * 4000; k >>= 2;
    p += (k & 3) * 1000; k >>= 2;
    p += (k & 3) * 250;  k >>= 2;
    p += (k & 1) * 125;  k >>= 1;
    p += (k % 5) * 25;   k /= 5;
    p += (k % 5) * 5;    k /= 5;
    p += k;
    return p;
}

// ---------------------------------------------------------------------------
// Kernel: count-sketch + circular convolution via packed FFT (p0 + i*p1).
// ---------------------------------------------------------------------------
__global__ __launch_bounds__(FBLK) void fft_conv_kernel(
    const float* __restrict__ x0, const float* __restrict__ x1,
    const int* __restrict__ h0, const int* __restrict__ h1,
    const int* __restrict__ s0, const int* __restrict__ s1,
    const float2* __restrict__ tw,
    unsigned short* __restrict__ zb)  // [Bsz, MMn] bf16
{
    extern __shared__ float2 X[];   // MMn complex = 128000 B
    const int b = blockIdx.x;
    const int tid = threadIdx.x;

    for (int i = tid; i < MMn; i += FBLK) X[i] = make_float2(0.f, 0.f);
    __syncthreads();

    for (int j = tid; j < D0n; j += FBLK) {
        float v = x0[(size_t)b * D0n + j] * (float)(2 * s0[j] - 1);
        atomicAdd(&X[h0[j]].x, v);
    }
    for (int j = tid; j < D1n; j += FBLK) {
        float v = x1[(size_t)b * D1n + j] * (float)(2 * s1[j] - 1);
        atomicAdd(&X[h1[j]].y, v);
    }
    __syncthreads();

    // forward (DIF, scrambled output)
    fft_stage<16000,4,false>(X, tw);         __syncthreads();
    fft_stage<4000, 4,false>(X, tw + 12000); __syncthreads();
    fft_stage<1000, 4,false>(X, tw + 15000); __syncthreads();
    fft_stage<250,  2,false>(X, tw + 15750); __syncthreads();
    fft_stage<125,  5,false>(X, tw + 15875); __syncthreads();
    fft_stage<25,   5,false>(X, tw + 15975); __syncthreads();
    fft_stage<5,    5,false>(X, tw);         __syncthreads();   // M=1: no twiddle

    // unpack packed spectra + pointwise product, in scrambled space
    for (int k = tid; k <= MMn / 2; k += FBLK) {
        if (k == 0 || k == MMn / 2) {
            int p = sigma_inv(k);
            float2 Q = X[p];
            X[p] = make_float2(Q.x * Q.y, 0.f);
        } else {
            int pa = sigma_inv(k), pb = sigma_inv(MMn - k);
            float2 Qa = X[pa], Qb = X[pb];
            float2 F0 = make_float2(0.5f * (Qa.x + Qb.x), 0.5f * (Qa.y - Qb.y));
            float2 dd = make_float2(Qa.x - Qb.x, Qa.y + Qb.y);
            float2 F1 = make_float2(0.5f * dd.y, -0.5f * dd.x);
            float2 H = cmul(F0, F1);
            X[pa] = H;
            X[pb] = make_float2(H.x, -H.y);
        }
    }
    __syncthreads();

    // inverse (stage inverses in reverse order -> natural output)
    fft_stage<5,    5,true>(X, tw);         __syncthreads();
    fft_stage<25,   5,true>(X, tw + 15975); __syncthreads();
    fft_stage<125,  5,true>(X, tw + 15875); __syncthreads();
    fft_stage<250,  2,true>(X, tw + 15750); __syncthreads();
    fft_stage<1000, 4,true>(X, tw + 15000); __syncthreads();
    fft_stage<4000, 4,true>(X, tw + 12000); __syncthreads();
    fft_stage<16000,4,true>(X, tw);         __syncthreads();

    const float invN = 1.0f / (float)MMn;
    unsigned short* zrow = zb + (size_t)b * MMn;
    for (int m = tid; m < MMn; m += FBLK) zrow[m] = f2bf(X[m].x * invN);
}

// ---------------------------------------------------------------------------
// W f32 -> bf16 (one-time, bandwidth-bound)
// ---------------------------------------------------------------------------
__global__ __launch_bounds__(256) void w2bf_kernel(
    const float* __restrict__ W, unsigned short* __restrict__ Wb)
{
    size_t i8 = ((size_t)blockIdx.x * 256 + threadIdx.x) * 8;
    if (i8 >= (size_t)OUTn * MMn) return;
    float4 a = *(const float4*)(W + i8);
    float4 b = *(const float4*)(W + i8 + 4);
    uint4 o;
    o.x = (uint32_t)f2bf(a.x) | ((uint32_t)f2bf(a.y) << 16);
    o.y = (uint32_t)f2bf(a.z) | ((uint32_t)f2bf(a.w) << 16);
    o.z = (uint32_t)f2bf(b.x) | ((uint32_t)f2bf(b.y) << 16);
    o.w = (uint32_t)f2bf(b.z) | ((uint32_t)f2bf(b.w) << 16);
    *(uint4*)(Wb + i8) = o;
}

// ---------------------------------------------------------------------------
// Split-K GEMM: partial[s] = Z[:, ks:ke] @ Wb[:, ks:ke]^T
// 128x128 tile, BK=64, global_load_lds 16B staging, XOR-8 LDS swizzle.
// Grid (24, 8, 4) = 768 blocks = 3/CU. Partials padded to 3072 cols.
// ---------------------------------------------------------------------------
#define PCOLS 3072
#define PSTRIDE ((size_t)Bsz * PCOLS)

__global__ __launch_bounds__(256, 3) void gemm_sk_kernel(
    const unsigned short* __restrict__ Z,    // [1024,16000] bf16
    const unsigned short* __restrict__ Wb,   // [3000,16000] bf16
    float* __restrict__ part)                // [4][1024][3072] f32
{
    __shared__ __align__(16) unsigned char As[16384];  // 128 rows x 64 bf16
    __shared__ __align__(16) unsigned char Bs[16384];

    const int tid = threadIdx.x;
    const int n0 = blockIdx.x * 128;
    const int m0 = blockIdx.y * 128;
    const int sp = blockIdx.z;
    const int lane = tid & 63;
    const int w = tid >> 6, wm = w >> 1, wn = w & 1;
    const int lr = lane & 15, qh = lane >> 4;

    // staging: 4 slots of 16B per matrix per thread; LDS slot = lane-contiguous,
    // global chunk q = (slot&7) ^ (row&7)  (XOR-8 swizzle)
    const unsigned char* aSrc[4]; const unsigned char* bSrc[4];
    int aLds[4], bLds[4];
#pragma unroll
    for (int i = 0; i < 4; i++) {
        int slot = i * 256 + tid;
        int r = slot >> 3, qp = slot & 7;
        int q = qp ^ (r & 7);
        aSrc[i] = (const unsigned char*)(Z + (size_t)(m0 + r) * MMn + q * 8);
        aLds[i] = slot * 16;
        int rw = n0 + r; if (rw > OUTn - 1) rw = OUTn - 1;   // tail clamp (discarded later)
        bSrc[i] = (const unsigned char*)(Wb + (size_t)rw * MMn + q * 8);
        bLds[i] = slot * 16;
    }

    // frag read byte offsets for kk=0; kk=1 is XOR 64 (chunk bit2 -> +4*16B)
    int aOff[4], bOff[4];
#pragma unroll
    for (int i = 0; i < 4; i++) {
        aOff[i] = (wm * 64 + i * 16 + lr) * 128 + ((qh ^ (lr & 7)) * 16);
        bOff[i] = (wn * 64 + i * 16 + lr) * 128 + ((qh ^ (lr & 7)) * 16);
    }

    f32x4 acc[4][4];
#pragma unroll
    for (int i = 0; i < 4; i++)
#pragma unroll
        for (int j = 0; j < 4; j++)
            acc[i][j] = (f32x4){0.f, 0.f, 0.f, 0.f};

    const int it_b = (250 * sp) / 4, it_e = (250 * (sp + 1)) / 4;
    for (int it = it_b; it < it_e; ++it) {
        const size_t koff = (size_t)it * 128;   // 64 bf16 = 128 bytes per iter
        __syncthreads();
#pragma unroll
        for (int i = 0; i < 4; i++) {
            gll16(aSrc[i] + koff, As + aLds[i]);
            gll16(bSrc[i] + koff, Bs + bLds[i]);
        }
        __syncthreads();
#pragma unroll
        for (int kk = 0; kk < 2; kk++) {
            const int kx = kk << 6;
            bf16x8 af[4], bfv[4];
#pragma unroll
            for (int i = 0; i < 4; i++) af[i]  = *(const bf16x8*)(As + (aOff[i] ^ kx));
#pragma unroll
            for (int j = 0; j < 4; j++) bfv[j] = *(const bf16x8*)(Bs + (bOff[j] ^ kx));
#pragma unroll
            for (int i = 0; i < 4; i++)
#pragma unroll
                for (int j = 0; j < 4; j++)
                    acc[i][j] = __builtin_amdgcn_mfma_f32_16x16x32_bf16(
                        af[i], bfv[j], acc[i][j], 0, 0, 0);
        }
    }

    float* pdst = part + (size_t)sp * PSTRIDE;
#pragma unroll
    for (int j = 0; j < 4; j++) {
        int n = n0 + wn * 64 + j * 16 + lr;
#pragma unroll
        for (int i = 0; i < 4; i++) {
            int mb = m0 + wm * 64 + i * 16 + qh * 4;
#pragma unroll
            for (int reg = 0; reg < 4; reg++)
                pdst[(size_t)(mb + reg) * PCOLS + n] = acc[i][j][reg];
        }
    }
}

// out = relu(sum_s part[s] + bias)
__global__ __launch_bounds__(256) void reduce_kernel(
    const float* __restrict__ part, const float* __restrict__ bias,
    float* __restrict__ out)
{
    int idx = blockIdx.x * 256 + threadIdx.x;   // 1024*750
    int b = idx / 750, oq = idx - b * 750;
    int o = oq * 4;
    const float* p = part + (size_t)b * PCOLS + o;
    float4 s0 = *(const float4*)(p);
    float4 s1 = *(const float4*)(p + PSTRIDE);
    float4 s2 = *(const float4*)(p + 2 * PSTRIDE);
    float4 s3 = *(const float4*)(p + 3 * PSTRIDE);
    float4 bv = *(const float4*)(bias + o);
    float4 r;
    r.x = s0.x + s1.x + s2.x + s3.x + bv.x; r.x = r.x > 0.f ? r.x : 0.f;
    r.y = s0.y + s1.y + s2.y + s3.y + bv.y; r.y = r.y > 0.f ? r.y : 0.f;
    r.z = s0.z + s1.z + s2.z + s3.z + bv.z; r.z = r.z > 0.f ? r.z : 0.f;
    r.w = s0.w + s1.w + s2.w + s3.w + bv.w; r.w = r.w > 0.f ? r.w : 0.f;
    *(float4*)(out + (size_t)b * OUTn + o) = r;
}

// ---------------------------------------------------------------------------
// Fallback GEMM (R2, validated): direct out, W f32 converted in-loop.
// Used only if ws_size can't hold the bf16-W + split-K partials.
// ---------------------------------------------------------------------------
#define BM 64
#define BN 128
#define BK 32
#define LDK 40

__global__ __launch_bounds__(256) void gemm_kernel(
    const unsigned short* __restrict__ Z, const float* __restrict__ W,
    const float* __restrict__ bias, float* __restrict__ out)
{
    __shared__ __align__(16) unsigned short As2[BM * LDK];
    __shared__ __align__(16) unsigned short Bs2[BN * LDK];

    const int tid = threadIdx.x;
    const int m0 = blockIdx.y * BM;
    const int n0 = blockIdx.x * BN;
    const int lane = tid & 63;
    const int w  = tid >> 6;
    const int wm = w >> 1;
    const int wn = w & 1;

    const int ar = tid >> 2, aq = tid & 3;
    const uint4* aSrc = (const uint4*)(Z + (size_t)(m0 + ar) * MMn + aq * 8);
    unsigned short* aDst = As2 + ar * LDK + aq * 8;

    const float4* bSrc[4];
    unsigned short* bDst[4];
#pragma unroll
    for (int p = 0; p < 4; p++) {
        int ch = tid + 256 * p;
        int r = ch >> 3, q = ch & 7;
        int rw = n0 + r; if (rw > OUTn - 1) rw = OUTn - 1;
        bSrc[p] = (const float4*)(W + (size_t)rw * MMn + q * 4);
        bDst[p] = Bs2 + r * LDK + q * 4;
    }

    const int qh = lane >> 4;
    const int lr = lane & 15;
    const unsigned short* aRd[2];
    const unsigned short* bRd[4];
#pragma unroll
    for (int i = 0; i < 2; i++) aRd[i] = As2 + (wm * 32 + i * 16 + lr) * LDK + qh * 8;
#pragma unroll
    for (int j = 0; j < 4; j++) bRd[j] = Bs2 + (wn * 64 + j * 16 + lr) * LDK + qh * 8;

    f32x4 acc[2][4];
#pragma unroll
    for (int i = 0; i < 2; i++)
#pragma unroll
        for (int j = 0; j < 4; j++)
            acc[i][j] = (f32x4){0.f, 0.f, 0.f, 0.f};

    for (int k0 = 0; k0 < MMn; k0 += BK) {
        uint4 av = aSrc[k0 >> 3];
        float4 bv[4];
#pragma unroll
        for (int p = 0; p < 4; p++) bv[p] = bSrc[p][k0 >> 2];

        __syncthreads();
        *(uint4*)aDst = av;
#pragma unroll
        for (int p = 0; p < 4; p++) {
            uint2 pk;
            pk.x = (uint32_t)f2bf(bv[p].x) | ((uint32_t)f2bf(bv[p].y) << 16);
            pk.y = (uint32_t)f2bf(bv[p].z) | ((uint32_t)f2bf(bv[p].w) << 16);
            *(uint2*)bDst[p] = pk;
        }
        __syncthreads();

        bf16x8 af[2], bfr[4];
#pragma unroll
        for (int i = 0; i < 2; i++) af[i] = *(const bf16x8*)aRd[i];
#pragma unroll
        for (int j = 0; j < 4; j++) bfr[j] = *(const bf16x8*)bRd[j];
#pragma unroll
        for (int i = 0; i < 2; i++)
#pragma unroll
            for (int j = 0; j < 4; j++)
                acc[i][j] = __builtin_amdgcn_mfma_f32_16x16x32_bf16(
                    af[i], bfr[j], acc[i][j], 0, 0, 0);
    }

#pragma unroll
    for (int j = 0; j < 4; j++) {
        int n = n0 + wn * 64 + j * 16 + lr;
        if (n < OUTn) {
            float bvb = bias[n];
#pragma unroll
            for (int i = 0; i < 2; i++) {
                int mb = m0 + wm * 32 + i * 16 + qh * 4;
#pragma unroll
                for (int reg = 0; reg < 4; reg++) {
                    float v = acc[i][j][reg] + bvb;
                    out[(size_t)(mb + reg) * OUTn + n] = v > 0.f ? v : 0.f;
                }
            }
        }
    }
}

// ---------------------------------------------------------------------------
// ws layout:
//   [0, 32768000)                zb   bf16 [1024][16000]
//   [32768000, 32896000)         tw   float2 [15995] (+pad)
//   [32896000, 128896000)        Wbf  bf16 [3000][16000]
//   [128896000, 179227648)       part f32 [4][1024][3072]
// ---------------------------------------------------------------------------
extern "C" void kernel_launch(void* const* d_in, const int* in_sizes, int n_in,
                              void* d_out, int out_size, void* d_ws, size_t ws_size,
                              hipStream_t stream) {
    const float* x0 = (const float*)d_in[0];
    const float* x1 = (const float*)d_in[1];
    const int*   h0 = (const int*)d_in[2];
    const int*   h1 = (const int*)d_in[3];
    const int*   s0 = (const int*)d_in[4];
    const int*   s1 = (const int*)d_in[5];
    const float* W  = (const float*)d_in[6];
    const float* bb = (const float*)d_in[7];
    float* out = (float*)d_out;

    unsigned char* ws = (unsigned char*)d_ws;
    unsigned short* zb  = (unsigned short*)(ws);
    float2*         tw  = (float2*)(ws + 32768000);
    unsigned short* wbf = (unsigned short*)(ws + 32896000);
    float*          prt = (float*)(ws + 128896000);
    const size_t NEED = 128896000 + 4 * PSTRIDE * sizeof(float);

    hipFuncSetAttribute((const void*)fft_conv_kernel,
                        hipFuncAttributeMaxDynamicSharedMemorySize, 131072);

    tw_init_kernel<<<(TWN + 255) / 256, 256, 0, stream>>>(tw);
    fft_conv_kernel<<<Bsz, FBLK, 128000, stream>>>(x0, x1, h0, h1, s0, s1, tw, zb);

    if (ws_size >= NEED) {
        size_t nW = (size_t)OUTn * MMn;
        w2bf_kernel<<<(int)((nW / 8 + 255) / 256), 256, 0, stream>>>(W, wbf);
        dim3 g((OUTn + 127) / 128, Bsz / 128, 4);   // 24 x 8 x 4 = 768
        gemm_sk_kernel<<<g, 256, 0, stream>>>(zb, wbf, prt);
        reduce_kernel<<<Bsz * (OUTn / 4) / 256, 256, 0, stream>>>(prt, bb, out);
    } else {
        dim3 g((OUTn + BN - 1) / BN, Bsz / BM);
        gemm_kernel<<<g, 256, 0, stream>>>(zb, W, bb, out);
    }
}

// Round 4
// 535.325 us; speedup vs baseline: 40.8939x; 1.0435x over previous
//
#include <hip/hip_runtime.h>
#include <stdint.h>

// Problem constants (MCB_42949672960828)
#define Bsz  1024
#define D0n  2048
#define D1n  2048
#define MMn  16000
#define OUTn 3000
#define FBLK 1024   // threads for FFT kernel (128KB LDS -> 1 block/CU; 16 waves)

typedef __attribute__((ext_vector_type(8))) short bf16x8;
typedef __attribute__((ext_vector_type(4))) float f32x4;

__device__ __forceinline__ unsigned short f2bf(float f) {
    union { float fv; uint32_t u; } v; v.fv = f;
    return (unsigned short)((v.u + 0x7fffu + ((v.u >> 16) & 1u)) >> 16);
}

__device__ __forceinline__ float2 operator+(float2 a, float2 b){ return make_float2(a.x+b.x, a.y+b.y); }
__device__ __forceinline__ float2 operator-(float2 a, float2 b){ return make_float2(a.x-b.x, a.y-b.y); }
__device__ __forceinline__ float2 operator*(float s, float2 a){ return make_float2(s*a.x, s*a.y); }
__device__ __forceinline__ float2 cmul(float2 a, float2 b){ return make_float2(a.x*b.x - a.y*b.y, a.x*b.y + a.y*b.x); }

// async 16B global -> LDS (direct-to-shared DMA)
__device__ __forceinline__ void gll16(const void* g, void* l) {
    __builtin_amdgcn_global_load_lds(
        (const __attribute__((address_space(1))) uint32_t*)g,
        (__attribute__((address_space(3))) uint32_t*)l, 16, 0, 0);
}

// ---------------------------------------------------------------------------
// Twiddle table, N = 16000, radices [16,8,5,5,5].
// Stage (NC,R,M): entries idx = p*(R-1)+(u-1) -> e^{-2pi i (p*u mod NC)/NC}
// offsets: (16000,16):0 len15000 | (1000,8):15000 len875 |
//          (125,5):15875 len100  | (25,5):15975 len20 | (5,5): none
// ---------------------------------------------------------------------------
#define TWN 15995

__global__ __launch_bounds__(256) void tw_init_kernel(float2* __restrict__ tw) {
    int g = blockIdx.x * 256 + threadIdx.x;
    if (g >= TWN) return;
    int NC, p, u;
    if (g < 15000)      { NC = 16000; int e = g;         p = e / 15; u = e % 15 + 1; }
    else if (g < 15875) { NC = 1000;  int e = g - 15000; p = e / 7;  u = e % 7 + 1; }
    else if (g < 15975) { NC = 125;   int e = g - 15875; p = e / 4;  u = e % 4 + 1; }
    else                { NC = 25;    int e = g - 15975; p = e / 4;  u = e % 4 + 1; }
    float ang = -6.28318530718f * (float)((p * u) % NC) / (float)NC;
    float s, c; __sincosf(ang, &s, &c);
    tw[g] = make_float2(c, s);
}

// radix-R DFT butterfly; sgn = -1 forward, +1 inverse (inverse = conj(DFT))
template<int R>
__device__ __forceinline__ void dft_r(const float2* a, float2* A, float sgn) {
    if constexpr (R == 2) {
        A[0] = a[0] + a[1];
        A[1] = a[0] - a[1];
    } else if constexpr (R == 4) {
        float2 t0 = a[0] + a[2], t1 = a[0] - a[2];
        float2 t2 = a[1] + a[3], t3 = a[1] - a[3];
        float2 it3 = make_float2(-sgn * t3.y, sgn * t3.x);
        A[0] = t0 + t2;  A[2] = t0 - t2;
        A[1] = t1 + it3; A[3] = t1 - it3;
    } else if constexpr (R == 5) {
        const float c1 = 0.30901699f,  s1 = 0.95105652f;
        const float c2 = -0.80901699f, s2 = 0.58778525f;
        float2 t1 = a[1] + a[4], t3 = a[1] - a[4];
        float2 t2 = a[2] + a[3], t4 = a[2] - a[3];
        float2 b1 = a[0] + c1 * t1 + c2 * t2;
        float2 b2 = a[0] + c2 * t1 + c1 * t2;
        float2 u  = s1 * t3 + s2 * t4;
        float2 v  = s2 * t3 - s1 * t4;
        float2 iu = make_float2(-sgn * u.y, sgn * u.x);
        float2 iv = make_float2(-sgn * v.y, sgn * v.x);
        A[0] = a[0] + t1 + t2;
        A[1] = b1 + iu;  A[4] = b1 - iu;
        A[2] = b2 + iv;  A[3] = b2 - iv;
    } else if constexpr (R == 8) {
        // n = n0 + 4*n1: DFT2 over n1, twiddle W8^{n0*k0}, DFT4 over n0
        const float H = 0.70710678f;
        float2 b0[4], b1[4];
#pragma unroll
        for (int n0 = 0; n0 < 4; n0++) {
            b0[n0] = a[n0] + a[n0 + 4];
            b1[n0] = a[n0] - a[n0 + 4];
        }
        // W8^e, rep (cos t, sgn*sin t): e=1:(H,H) e=2:(0,1) e=3:(-H,H)
        b1[1] = cmul(b1[1], make_float2(H, sgn * H));
        b1[2] = cmul(b1[2], make_float2(0.f, sgn));
        b1[3] = cmul(b1[3], make_float2(-H, sgn * H));
        float2 o[4];
        dft_r<4>(b0, o, sgn);
        A[0] = o[0]; A[2] = o[1]; A[4] = o[2]; A[6] = o[3];
        dft_r<4>(b1, o, sgn);
        A[1] = o[0]; A[3] = o[1]; A[5] = o[2]; A[7] = o[3];
    } else {  // R == 16: n = n0 + 4*n1: DFT4 over n1, W16^{n0*k0}, DFT4 over n0
        const float C1 = 0.92387953f, S1 = 0.38268343f;  // theta = 2pi/16
        const float C2 = 0.70710678f, S2 = 0.70710678f;  // 2*
        const float C3 = 0.38268343f, S3 = 0.92387953f;  // 3*
        float2 b[4][4];
#pragma unroll
        for (int n0 = 0; n0 < 4; n0++) {
            float2 t[4] = { a[n0], a[n0 + 4], a[n0 + 8], a[n0 + 12] };
            dft_r<4>(t, b[n0], sgn);
        }
        // internal twiddles W16^{n0*k0}; rep (cos t_e, sgn*sin t_e)
        b[1][1] = cmul(b[1][1], make_float2(C1, sgn * S1));   // e=1
        b[1][2] = cmul(b[1][2], make_float2(C2, sgn * S2));   // e=2
        b[1][3] = cmul(b[1][3], make_float2(C3, sgn * S3));   // e=3
        b[2][1] = cmul(b[2][1], make_float2(C2, sgn * S2));   // e=2
        b[2][2] = cmul(b[2][2], make_float2(0.f, sgn));       // e=4
        b[2][3] = cmul(b[2][3], make_float2(-C2, sgn * S2));  // e=6
        b[3][1] = cmul(b[3][1], make_float2(C3, sgn * S3));   // e=3
        b[3][2] = cmul(b[3][2], make_float2(-C2, sgn * S2));  // e=6
        b[3][3] = cmul(b[3][3], make_float2(-C1, -sgn * S1)); // e=9: (cos202.5, sgn*sin202.5)
#pragma unroll
        for (int k0 = 0; k0 < 4; k0++) {
            float2 t[4] = { b[0][k0], b[1][k0], b[2][k0], b[3][k0] };
            float2 o[4];
            dft_r<4>(t, o, sgn);
            A[k0] = o[0]; A[k0 + 4] = o[1]; A[k0 + 8] = o[2]; A[k0 + 12] = o[3];
        }
    }
}

// In-place stage; twiddles from table (inverse = conjugate).
template<int NC, int R, bool INV>
__device__ __forceinline__ void fft_stage(float2* X, const float2* __restrict__ tw) {
    constexpr int M = NC / R;
    constexpr int NBF = MMn / R;
    constexpr float sgn = INV ? 1.0f : -1.0f;
    for (int e = threadIdx.x; e < NBF; e += FBLK) {
        const int blk = e / M;
        const int p   = e - blk * M;
        const int base = blk * NC + p;
        float2 a[R];
#pragma unroll
        for (int t = 0; t < R; t++) a[t] = X[base + M * t];
        if constexpr (INV && M > 1) {
#pragma unroll
            for (int u = 1; u < R; u++) {
                float2 w = tw[p * (R - 1) + (u - 1)];
                a[u] = cmul(a[u], make_float2(w.x, -w.y));
            }
        }
        float2 A[R];
        dft_r<R>(a, A, sgn);
        if constexpr (!INV && M > 1) {
#pragma unroll
            for (int u = 1; u < R; u++) {
                float2 w = tw[p * (R - 1) + (u - 1)];
                A[u] = cmul(A[u], w);
            }
        }
#pragma unroll
        for (int t = 0; t < R; t++) X[base + M * t] = A[t];
    }
}

// position of natural frequency k in the DIF-scrambled array.
// k in mixed radix (16,8,5,5,5) from LSD; weights N/(r1..ri) = (1000,125,25,5,1)
__device__ __forceinline__ int sigma_inv(int k) {
    int p = (k & 15) * 1000; k >>= 4;
    p += (k & 7) * 125;      k >>= 3;
    p += (k % 5) * 25;       k /= 5;
    p += (k % 5) * 5;        k /= 5;
    p += k;
    return p;
}

// ---------------------------------------------------------------------------
// Kernel: count-sketch + circular convolution via packed FFT (p0 + i*p1),
// with W f32->bf16 conversion fused in (loads issued early, consumed a full
// FFT stage later so the 288 MB of traffic hides under VALU/LDS work).
// ---------------------------------------------------------------------------
#define WU_TOT 12000000   // (OUTn*MMn)/4 float4 units
#define WU_STRIDE (Bsz * FBLK)

__global__ __launch_bounds__(FBLK) void fft_conv_kernel(
    const float* __restrict__ x0, const float* __restrict__ x1,
    const int* __restrict__ h0, const int* __restrict__ h1,
    const int* __restrict__ s0, const int* __restrict__ s1,
    const float2* __restrict__ tw,
    const float* __restrict__ W, unsigned short* __restrict__ wbf, int doW,
    unsigned short* __restrict__ zb)  // [Bsz, MMn] bf16
{
    extern __shared__ float2 X[];   // MMn complex = 128000 B
    const int b = blockIdx.x;
    const int tid = threadIdx.x;
    const int uid = b * FBLK + tid;
    const float4* wsrc = (const float4*)W;

    float4 wr[4];
    // batch 0 issue (units uid + {0..3}*WU_STRIDE)
    if (doW) {
#pragma unroll
        for (int j = 0; j < 4; j++) {
            size_t u = (size_t)uid + (size_t)j * WU_STRIDE;
            if (u < WU_TOT) wr[j] = wsrc[u];
        }
    }

    for (int i = tid; i < MMn; i += FBLK) X[i] = make_float2(0.f, 0.f);
    __syncthreads();

    for (int j = tid; j < D0n; j += FBLK) {
        float v = x0[(size_t)b * D0n + j] * (float)(2 * s0[j] - 1);
        atomicAdd(&X[h0[j]].x, v);
    }
    for (int j = tid; j < D1n; j += FBLK) {
        float v = x1[(size_t)b * D1n + j] * (float)(2 * s1[j] - 1);
        atomicAdd(&X[h1[j]].y, v);
    }
    __syncthreads();

    fft_stage<16000,16,false>(X, tw);        __syncthreads();

    // batch 0 consume, batch 1 issue
    if (doW) {
#pragma unroll
        for (int j = 0; j < 4; j++) {
            size_t u = (size_t)uid + (size_t)j * WU_STRIDE;
            if (u < WU_TOT) {
                uint2 pk;
                pk.x = (uint32_t)f2bf(wr[j].x) | ((uint32_t)f2bf(wr[j].y) << 16);
                pk.y = (uint32_t)f2bf(wr[j].z) | ((uint32_t)f2bf(wr[j].w) << 16);
                ((uint2*)wbf)[u] = pk;
            }
        }
#pragma unroll
        for (int j = 0; j < 4; j++) {
            size_t u = (size_t)uid + (size_t)(j + 4) * WU_STRIDE;
            if (u < WU_TOT) wr[j] = wsrc[u];
        }
    }

    fft_stage<1000, 8,false>(X, tw + 15000); __syncthreads();

    // batch 1 consume, batch 2 issue
    if (doW) {
#pragma unroll
        for (int j = 0; j < 4; j++) {
            size_t u = (size_t)uid + (size_t)(j + 4) * WU_STRIDE;
            if (u < WU_TOT) {
                uint2 pk;
                pk.x = (uint32_t)f2bf(wr[j].x) | ((uint32_t)f2bf(wr[j].y) << 16);
                pk.y = (uint32_t)f2bf(wr[j].z) | ((uint32_t)f2bf(wr[j].w) << 16);
                ((uint2*)wbf)[u] = pk;
            }
        }
#pragma unroll
        for (int j = 0; j < 4; j++) {
            size_t u = (size_t)uid + (size_t)(j + 8) * WU_STRIDE;
            if (u < WU_TOT) wr[j] = wsrc[u];
        }
    }

    fft_stage<125,  5,false>(X, tw + 15875); __syncthreads();

    // batch 2 consume
    if (doW) {
#pragma unroll
        for (int j = 0; j < 4; j++) {
            size_t u = (size_t)uid + (size_t)(j + 8) * WU_STRIDE;
            if (u < WU_TOT) {
                uint2 pk;
                pk.x = (uint32_t)f2bf(wr[j].x) | ((uint32_t)f2bf(wr[j].y) << 16);
                pk.y = (uint32_t)f2bf(wr[j].z) | ((uint32_t)f2bf(wr[j].w) << 16);
                ((uint2*)wbf)[u] = pk;
            }
        }
    }

    fft_stage<25,   5,false>(X, tw + 15975); __syncthreads();
    fft_stage<5,    5,false>(X, tw);         __syncthreads();   // M=1: no twiddle

    // unpack packed spectra + pointwise product, in scrambled space
    for (int k = tid; k <= MMn / 2; k += FBLK) {
        if (k == 0 || k == MMn / 2) {
            int p = sigma_inv(k);
            float2 Q = X[p];
            X[p] = make_float2(Q.x * Q.y, 0.f);
        } else {
            int pa = sigma_inv(k), pb = sigma_inv(MMn - k);
            float2 Qa = X[pa], Qb = X[pb];
            float2 F0 = make_float2(0.5f * (Qa.x + Qb.x), 0.5f * (Qa.y - Qb.y));
            float2 dd = make_float2(Qa.x - Qb.x, Qa.y + Qb.y);
            float2 F1 = make_float2(0.5f * dd.y, -0.5f * dd.x);
            float2 H = cmul(F0, F1);
            X[pa] = H;
            X[pb] = make_float2(H.x, -H.y);
        }
    }
    __syncthreads();

    // inverse (stage inverses in reverse order -> natural output)
    fft_stage<5,    5,true>(X, tw);         __syncthreads();
    fft_stage<25,   5,true>(X, tw + 15975); __syncthreads();
    fft_stage<125,  5,true>(X, tw + 15875); __syncthreads();
    fft_stage<1000, 8,true>(X, tw + 15000); __syncthreads();
    fft_stage<16000,16,true>(X, tw);        __syncthreads();

    const float invN = 1.0f / (float)MMn;
    unsigned short* zrow = zb + (size_t)b * MMn;
    for (int m = tid; m < MMn; m += FBLK) zrow[m] = f2bf(X[m].x * invN);
}

// ---------------------------------------------------------------------------
// Split-K GEMM: partial[s] = Z[:, ks:ke] @ Wb[:, ks:ke]^T  (validated R3)
// ---------------------------------------------------------------------------
#define PCOLS 3072
#define PSTRIDE ((size_t)Bsz * PCOLS)

__global__ __launch_bounds__(256, 3) void gemm_sk_kernel(
    const unsigned short* __restrict__ Z,    // [1024,16000] bf16
    const unsigned short* __restrict__ Wb,   // [3000,16000] bf16
    float* __restrict__ part)                // [4][1024][3072] f32
{
    __shared__ __align__(16) unsigned char As[16384];
    __shared__ __align__(16) unsigned char Bs[16384];

    const int tid = threadIdx.x;
    const int n0 = blockIdx.x * 128;
    const int m0 = blockIdx.y * 128;
    const int sp = blockIdx.z;
    const int lane = tid & 63;
    const int w = tid >> 6, wm = w >> 1, wn = w & 1;
    const int lr = lane & 15, qh = lane >> 4;

    const unsigned char* aSrc[4]; const unsigned char* bSrc[4];
    int aLds[4], bLds[4];
#pragma unroll
    for (int i = 0; i < 4; i++) {
        int slot = i * 256 + tid;
        int r = slot >> 3, qp = slot & 7;
        int q = qp ^ (r & 7);
        aSrc[i] = (const unsigned char*)(Z + (size_t)(m0 + r) * MMn + q * 8);
        aLds[i] = slot * 16;
        int rw = n0 + r; if (rw > OUTn - 1) rw = OUTn - 1;
        bSrc[i] = (const unsigned char*)(Wb + (size_t)rw * MMn + q * 8);
        bLds[i] = slot * 16;
    }

    int aOff[4], bOff[4];
#pragma unroll
    for (int i = 0; i < 4; i++) {
        aOff[i] = (wm * 64 + i * 16 + lr) * 128 + ((qh ^ (lr & 7)) * 16);
        bOff[i] = (wn * 64 + i * 16 + lr) * 128 + ((qh ^ (lr & 7)) * 16);
    }

    f32x4 acc[4][4];
#pragma unroll
    for (int i = 0; i < 4; i++)
#pragma unroll
        for (int j = 0; j < 4; j++)
            acc[i][j] = (f32x4){0.f, 0.f, 0.f, 0.f};

    const int it_b = (250 * sp) / 4, it_e = (250 * (sp + 1)) / 4;
    for (int it = it_b; it < it_e; ++it) {
        const size_t koff = (size_t)it * 128;
        __syncthreads();
#pragma unroll
        for (int i = 0; i < 4; i++) {
            gll16(aSrc[i] + koff, As + aLds[i]);
            gll16(bSrc[i] + koff, Bs + bLds[i]);
        }
        __syncthreads();
#pragma unroll
        for (int kk = 0; kk < 2; kk++) {
            const int kx = kk << 6;
            bf16x8 af[4], bfv[4];
#pragma unroll
            for (int i = 0; i < 4; i++) af[i]  = *(const bf16x8*)(As + (aOff[i] ^ kx));
#pragma unroll
            for (int j = 0; j < 4; j++) bfv[j] = *(const bf16x8*)(Bs + (bOff[j] ^ kx));
#pragma unroll
            for (int i = 0; i < 4; i++)
#pragma unroll
                for (int j = 0; j < 4; j++)
                    acc[i][j] = __builtin_amdgcn_mfma_f32_16x16x32_bf16(
                        af[i], bfv[j], acc[i][j], 0, 0, 0);
        }
    }

    float* pdst = part + (size_t)sp * PSTRIDE;
#pragma unroll
    for (int j = 0; j < 4; j++) {
        int n = n0 + wn * 64 + j * 16 + lr;
#pragma unroll
        for (int i = 0; i < 4; i++) {
            int mb = m0 + wm * 64 + i * 16 + qh * 4;
#pragma unroll
            for (int reg = 0; reg < 4; reg++)
                pdst[(size_t)(mb + reg) * PCOLS + n] = acc[i][j][reg];
        }
    }
}

// out = relu(sum_s part[s] + bias)
__global__ __launch_bounds__(256) void reduce_kernel(
    const float* __restrict__ part, const float* __restrict__ bias,
    float* __restrict__ out)
{
    int idx = blockIdx.x * 256 + threadIdx.x;
    int b = idx / 750, oq = idx - b * 750;
    int o = oq * 4;
    const float* p = part + (size_t)b * PCOLS + o;
    float4 s0 = *(const float4*)(p);
    float4 s1 = *(const float4*)(p + PSTRIDE);
    float4 s2 = *(const float4*)(p + 2 * PSTRIDE);
    float4 s3 = *(const float4*)(p + 3 * PSTRIDE);
    float4 bv = *(const float4*)(bias + o);
    float4 r;
    r.x = s0.x + s1.x + s2.x + s3.x + bv.x; r.x = r.x > 0.f ? r.x : 0.f;
    r.y = s0.y + s1.y + s2.y + s3.y + bv.y; r.y = r.y > 0.f ? r.y : 0.f;
    r.z = s0.z + s1.z + s2.z + s3.z + bv.z; r.z = r.z > 0.f ? r.z : 0.f;
    r.w = s0.w + s1.w + s2.w + s3.w + bv.w; r.w = r.w > 0.f ? r.w : 0.f;
    *(float4*)(out + (size_t)b * OUTn + o) = r;
}

// ---------------------------------------------------------------------------
// Fallback GEMM (R2, validated): direct out, W f32 converted in-loop.
// ---------------------------------------------------------------------------
#define BM 64
#define BN 128
#define BK 32
#define LDK 40

__global__ __launch_bounds__(256) void gemm_kernel(
    const unsigned short* __restrict__ Z, const float* __restrict__ W,
    const float* __restrict__ bias, float* __restrict__ out)
{
    __shared__ __align__(16) unsigned short As2[BM * LDK];
    __shared__ __align__(16) unsigned short Bs2[BN * LDK];

    const int tid = threadIdx.x;
    const int m0 = blockIdx.y * BM;
    const int n0 = blockIdx.x * BN;
    const int lane = tid & 63;
    const int w  = tid >> 6;
    const int wm = w >> 1;
    const int wn = w & 1;

    const int ar = tid >> 2, aq = tid & 3;
    const uint4* aSrc = (const uint4*)(Z + (size_t)(m0 + ar) * MMn + aq * 8);
    unsigned short* aDst = As2 + ar * LDK + aq * 8;

    const float4* bSrc[4];
    unsigned short* bDst[4];
#pragma unroll
    for (int p = 0; p < 4; p++) {
        int ch = tid + 256 * p;
        int r = ch >> 3, q = ch & 7;
        int rw = n0 + r; if (rw > OUTn - 1) rw = OUTn - 1;
        bSrc[p] = (const float4*)(W + (size_t)rw * MMn + q * 4);
        bDst[p] = Bs2 + r * LDK + q * 4;
    }

    const int qh = lane >> 4;
    const int lr = lane & 15;
    const unsigned short* aRd[2];
    const unsigned short* bRd[4];
#pragma unroll
    for (int i = 0; i < 2; i++) aRd[i] = As2 + (wm * 32 + i * 16 + lr) * LDK + qh * 8;
#pragma unroll
    for (int j = 0; j < 4; j++) bRd[j] = Bs2 + (wn * 64 + j * 16 + lr) * LDK + qh * 8;

    f32x4 acc[2][4];
#pragma unroll
    for (int i = 0; i < 2; i++)
#pragma unroll
        for (int j = 0; j < 4; j++)
            acc[i][j] = (f32x4){0.f, 0.f, 0.f, 0.f};

    for (int k0 = 0; k0 < MMn; k0 += BK) {
        uint4 av = aSrc[k0 >> 3];
        float4 bv[4];
#pragma unroll
        for (int p = 0; p < 4; p++) bv[p] = bSrc[p][k0 >> 2];

        __syncthreads();
        *(uint4*)aDst = av;
#pragma unroll
        for (int p = 0; p < 4; p++) {
            uint2 pk;
            pk.x = (uint32_t)f2bf(bv[p].x) | ((uint32_t)f2bf(bv[p].y) << 16);
            pk.y = (uint32_t)f2bf(bv[p].z) | ((uint32_t)f2bf(bv[p].w) << 16);
            *(uint2*)bDst[p] = pk;
        }
        __syncthreads();

        bf16x8 af[2], bfr[4];
#pragma unroll
        for (int i = 0; i < 2; i++) af[i] = *(const bf16x8*)aRd[i];
#pragma unroll
        for (int j = 0; j < 4; j++) bfr[j] = *(const bf16x8*)bRd[j];
#pragma unroll
        for (int i = 0; i < 2; i++)
#pragma unroll
            for (int j = 0; j < 4; j++)
                acc[i][j] = __builtin_amdgcn_mfma_f32_16x16x32_bf16(
                    af[i], bfr[j], acc[i][j], 0, 0, 0);
    }

#pragma unroll
    for (int j = 0; j < 4; j++) {
        int n = n0 + wn * 64 + j * 16 + lr;
        if (n < OUTn) {
            float bvb = bias[n];
#pragma unroll
            for (int i = 0; i < 2; i++) {
                int mb = m0 + wm * 32 + i * 16 + qh * 4;
#pragma unroll
                for (int reg = 0; reg < 4; reg++) {
                    float v = acc[i][j][reg] + bvb;
                    out[(size_t)(mb + reg) * OUTn + n] = v > 0.f ? v : 0.f;
                }
            }
        }
    }
}

// ---------------------------------------------------------------------------
// ws layout:
//   [0, 32768000)                zb   bf16 [1024][16000]
//   [32768000, 32896000)         tw   float2 [15995] (+pad)
//   [32896000, 128896000)        Wbf  bf16 [3000][16000]
//   [128896000, 179227648)       part f32 [4][1024][3072]
// ---------------------------------------------------------------------------
extern "C" void kernel_launch(void* const* d_in, const int* in_sizes, int n_in,
                              void* d_out, int out_size, void* d_ws, size_t ws_size,
                              hipStream_t stream) {
    const float* x0 = (const float*)d_in[0];
    const float* x1 = (const float*)d_in[1];
    const int*   h0 = (const int*)d_in[2];
    const int*   h1 = (const int*)d_in[3];
    const int*   s0 = (const int*)d_in[4];
    const int*   s1 = (const int*)d_in[5];
    const float* W  = (const float*)d_in[6];
    const float* bb = (const float*)d_in[7];
    float* out = (float*)d_out;

    unsigned char* ws = (unsigned char*)d_ws;
    unsigned short* zb  = (unsigned short*)(ws);
    float2*         tw  = (float2*)(ws + 32768000);
    unsigned short* wbf = (unsigned short*)(ws + 32896000);
    float*          prt = (float*)(ws + 128896000);
    const size_t NEED = 128896000 + 4 * PSTRIDE * sizeof(float);
    const int doW = (ws_size >= NEED) ? 1 : 0;

    hipFuncSetAttribute((const void*)fft_conv_kernel,
                        hipFuncAttributeMaxDynamicSharedMemorySize, 131072);

    tw_init_kernel<<<(TWN + 255) / 256, 256, 0, stream>>>(tw);
    fft_conv_kernel<<<Bsz, FBLK, 128000, stream>>>(x0, x1, h0, h1, s0, s1, tw,
                                                   W, wbf, doW, zb);

    if (doW) {
        dim3 g((OUTn + 127) / 128, Bsz / 128, 4);
        gemm_sk_kernel<<<g, 256, 0, stream>>>(zb, wbf, prt);
        reduce_kernel<<<Bsz * (OUTn / 4) / 256, 256, 0, stream>>>(prt, bb, out);
    } else {
        dim3 g((OUTn + BN - 1) / BN, Bsz / BM);
        gemm_kernel<<<g, 256, 0, stream>>>(zb, W, bb, out);
    }
}

// Round 5
// 511.974 us; speedup vs baseline: 42.7591x; 1.0456x over previous
//
#include <hip/hip_runtime.h>
#include <stdint.h>

// Problem constants (MCB_42949672960828)
#define Bsz  1024
#define D0n  2048
#define D1n  2048
#define MMn  16000
#define N2   8000    // half-length complex FFT size
#define OUTn 3000
#define FBLK 512     // threads for FFT kernel (64KB LDS -> 2 blocks/CU)

typedef __attribute__((ext_vector_type(8))) short bf16x8;
typedef __attribute__((ext_vector_type(4))) float f32x4;

__device__ __forceinline__ unsigned short f2bf(float f) {
    union { float fv; uint32_t u; } v; v.fv = f;
    return (unsigned short)((v.u + 0x7fffu + ((v.u >> 16) & 1u)) >> 16);
}
__device__ __forceinline__ float2 bf2c(uint32_t v) {
    union { uint32_t u; float f; } a, b;
    a.u = v << 16; b.u = v & 0xffff0000u;
    return make_float2(a.f, b.f);
}

__device__ __forceinline__ float2 operator+(float2 a, float2 b){ return make_float2(a.x+b.x, a.y+b.y); }
__device__ __forceinline__ float2 operator-(float2 a, float2 b){ return make_float2(a.x-b.x, a.y-b.y); }
__device__ __forceinline__ float2 operator*(float s, float2 a){ return make_float2(s*a.x, s*a.y); }
__device__ __forceinline__ float2 cmul(float2 a, float2 b){ return make_float2(a.x*b.x - a.y*b.y, a.x*b.y + a.y*b.x); }

// async 16B global -> LDS (direct-to-shared DMA)
__device__ __forceinline__ void gll16(const void* g, void* l) {
    __builtin_amdgcn_global_load_lds(
        (const __attribute__((address_space(1))) uint32_t*)g,
        (__attribute__((address_space(3))) uint32_t*)l, 16, 0, 0);
}

// ---------------------------------------------------------------------------
// Twiddle table, N2 = 8000, radices [20,20,20].
// stage1 (NC=8000,M=400): tw[p*19+(u-1)] p<400       -> [0,7600)
// stage2 (NC=400, M=20):  tw[7600+p*19+(u-1)] p<20   -> [7600,7980)
// untangle: utw[k] = e^{-2pi i k/8000}, k<=4000      -> [7980,11981)
// ---------------------------------------------------------------------------
#define TWN 11981

__global__ __launch_bounds__(256) void tw_init_kernel(float2* __restrict__ tw) {
    int g = blockIdx.x * 256 + threadIdx.x;
    if (g >= TWN) return;
    float ang;
    if (g < 7600)      { int p = g / 19, u = g % 19 + 1;
                         ang = -6.28318530718f * (float)((p * u) % 8000) / 8000.f; }
    else if (g < 7980) { int e = g - 7600; int p = e / 19, u = e % 19 + 1;
                         ang = -6.28318530718f * (float)((p * u) % 400) / 400.f; }
    else               { int k = g - 7980;
                         ang = -6.28318530718f * (float)k / 8000.f; }
    float s, c; __sincosf(ang, &s, &c);
    tw[g] = make_float2(c, s);
}

// radix-R DFT butterfly; sgn = -1 forward, +1 inverse
template<int R>
__device__ __forceinline__ void dft_r(const float2* a, float2* A, float sgn) {
    if constexpr (R == 4) {
        float2 t0 = a[0] + a[2], t1 = a[0] - a[2];
        float2 t2 = a[1] + a[3], t3 = a[1] - a[3];
        float2 it3 = make_float2(-sgn * t3.y, sgn * t3.x);
        A[0] = t0 + t2;  A[2] = t0 - t2;
        A[1] = t1 + it3; A[3] = t1 - it3;
    } else if constexpr (R == 5) {
        const float c1 = 0.30901699f,  s1 = 0.95105652f;
        const float c2 = -0.80901699f, s2 = 0.58778525f;
        float2 t1 = a[1] + a[4], t3 = a[1] - a[4];
        float2 t2 = a[2] + a[3], t4 = a[2] - a[3];
        float2 b1 = a[0] + c1 * t1 + c2 * t2;
        float2 b2 = a[0] + c2 * t1 + c1 * t2;
        float2 u  = s1 * t3 + s2 * t4;
        float2 v  = s2 * t3 - s1 * t4;
        float2 iu = make_float2(-sgn * u.y, sgn * u.x);
        float2 iv = make_float2(-sgn * v.y, sgn * v.x);
        A[0] = a[0] + t1 + t2;
        A[1] = b1 + iu;  A[4] = b1 - iu;
        A[2] = b2 + iv;  A[3] = b2 - iv;
    } else {  // R == 20: n = n0 + 4*n1 (n0<4,n1<5), k = k1 + 5*k0 (k1<5,k0<4)
        // inner DFT5 over n1 -> b[n0][k1]; twiddle W20^{n0*k1}; outer DFT4 over n0
        float2 b[4][5];
#pragma unroll
        for (int n0 = 0; n0 < 4; n0++) {
            float2 t[5] = { a[n0], a[n0+4], a[n0+8], a[n0+12], a[n0+16] };
            dft_r<5>(t, b[n0], sgn);
        }
        // W20^e as (cos(2pi e/20), sgn*sin(2pi e/20))
        const float E1c=0.95105652f,  E1s=0.30901699f;
        const float E2c=0.80901699f,  E2s=0.58778525f;
        const float E3c=0.58778525f,  E3s=0.80901699f;
        const float E4c=0.30901699f,  E4s=0.95105652f;
        const float E6c=-0.30901699f, E6s=0.95105652f;
        const float E8c=-0.80901699f, E8s=0.58778525f;
        const float E9c=-0.95105652f, E9s=0.30901699f;
        const float E12c=-0.80901699f,E12s=-0.58778525f;
        b[1][1] = cmul(b[1][1], make_float2(E1c,  sgn*E1s));
        b[1][2] = cmul(b[1][2], make_float2(E2c,  sgn*E2s));
        b[1][3] = cmul(b[1][3], make_float2(E3c,  sgn*E3s));
        b[1][4] = cmul(b[1][4], make_float2(E4c,  sgn*E4s));
        b[2][1] = cmul(b[2][1], make_float2(E2c,  sgn*E2s));
        b[2][2] = cmul(b[2][2], make_float2(E4c,  sgn*E4s));
        b[2][3] = cmul(b[2][3], make_float2(E6c,  sgn*E6s));
        b[2][4] = cmul(b[2][4], make_float2(E8c,  sgn*E8s));
        b[3][1] = cmul(b[3][1], make_float2(E3c,  sgn*E3s));
        b[3][2] = cmul(b[3][2], make_float2(E6c,  sgn*E6s));
        b[3][3] = cmul(b[3][3], make_float2(E9c,  sgn*E9s));
        b[3][4] = cmul(b[3][4], make_float2(E12c, sgn*E12s));
#pragma unroll
        for (int k1 = 0; k1 < 5; k1++) {
            float2 t[4] = { b[0][k1], b[1][k1], b[2][k1], b[3][k1] };
            float2 o[4];
            dft_r<4>(t, o, sgn);
            A[k1] = o[0]; A[k1+5] = o[1]; A[k1+10] = o[2]; A[k1+15] = o[3];
        }
    }
}

// In-place stage over N-point buffer; twiddles from table (inverse = conj).
template<int N, int NC, int R, bool INV>
__device__ __forceinline__ void fft_stage(float2* X, const float2* __restrict__ tw) {
    constexpr int M = NC / R;
    constexpr int NBF = N / R;
    constexpr float sgn = INV ? 1.0f : -1.0f;
    for (int e = threadIdx.x; e < NBF; e += FBLK) {
        const int blk = e / M;
        const int p   = e - blk * M;
        const int base = blk * NC + p;
        float2 a[R];
#pragma unroll
        for (int t = 0; t < R; t++) a[t] = X[base + M * t];
        if constexpr (INV && M > 1) {
#pragma unroll
            for (int u = 1; u < R; u++) {
                float2 w = tw[p * (R - 1) + (u - 1)];
                a[u] = cmul(a[u], make_float2(w.x, -w.y));
            }
        }
        float2 A[R];
        dft_r<R>(a, A, sgn);
        if constexpr (!INV && M > 1) {
#pragma unroll
            for (int u = 1; u < R; u++) {
                float2 w = tw[p * (R - 1) + (u - 1)];
                A[u] = cmul(A[u], w);
            }
        }
#pragma unroll
        for (int t = 0; t < R; t++) X[base + M * t] = A[t];
    }
}

// scrambled position of natural frequency k; radices (20,20,20), weights (400,20,1)
__device__ __forceinline__ int sigma_inv8k(int k) {
    return (k % 20) * 400 + ((k / 20) % 20) * 20 + (k / 400);
}

// W conversion plumbing (fused into fft kernel; 6 batches of 4 float4/thread)
#define WU_TOT 12000000            // (OUTn*MMn)/4 float4 units
#define WU_STRIDE (Bsz * FBLK)     // 524288

__device__ __forceinline__ void w_issue(const float4* __restrict__ wsrc,
                                        float4* wr, int uid, int bi) {
#pragma unroll
    for (int j = 0; j < 4; j++) {
        size_t u = (size_t)uid + (size_t)(bi * 4 + j) * WU_STRIDE;
        if (u < WU_TOT) wr[j] = wsrc[u];
    }
}
__device__ __forceinline__ void w_consume(unsigned short* __restrict__ wbf,
                                          const float4* wr, int uid, int bi) {
#pragma unroll
    for (int j = 0; j < 4; j++) {
        size_t u = (size_t)uid + (size_t)(bi * 4 + j) * WU_STRIDE;
        if (u < WU_TOT) {
            uint2 pk;
            pk.x = (uint32_t)f2bf(wr[j].x) | ((uint32_t)f2bf(wr[j].y) << 16);
            pk.y = (uint32_t)f2bf(wr[j].z) | ((uint32_t)f2bf(wr[j].w) << 16);
            ((uint2*)wbf)[u] = pk;
        }
    }
}

// ---------------------------------------------------------------------------
// Kernel: count-sketch + circular convolution via even/odd packed half-length
// FFTs. c[n] = p[2n] + i p[2n+1]  ==> float layout of c == float layout of p,
// so scatter/output are identity on float addressing.
// FFT8000(c0) -> spill bf16; FFT8000(c1) in LDS; untangle-multiply-retangle:
//   E=(Ca+conj(Cb))/2, O=(Ca-conj(Cb))/(2i),
//   Ez=E0E1+W^k O0O1 (W=e^{-2pi i/8000}), Oz=E0O1+O0E1, D=Ez+iOz,
//   D[8000-k]=conj(Ez)+i conj(Oz);
// IFFT8000(D)/8000 -> z interleaved. 64 KB LDS -> 2 blocks/CU.
// ---------------------------------------------------------------------------
__global__ __launch_bounds__(FBLK, 4) void fft_conv_kernel(
    const float* __restrict__ x0, const float* __restrict__ x1,
    const int* __restrict__ h0, const int* __restrict__ h1,
    const int* __restrict__ s0, const int* __restrict__ s1,
    const float2* __restrict__ tw,
    const float* __restrict__ W, unsigned short* __restrict__ wbf, int doW,
    uint32_t* __restrict__ c0g,       // [Bsz, 8000] bf16-pair spill
    unsigned short* __restrict__ zb)  // [Bsz, MMn] bf16
{
    __shared__ float2 X[N2];          // 64000 B
    const int b = blockIdx.x;
    const int tid = threadIdx.x;
    const int uid = b * FBLK + tid;
    const float4* wsrc = (const float4*)W;
    const float2* utw = tw + 7980;
    float* Xf = (float*)X;
    uint32_t* c0row = c0g + (size_t)b * N2;

    float4 wr[4];
    if (doW) w_issue(wsrc, wr, uid, 0);

    // ---- FFT of c0 ----
    for (int i = tid; i < N2; i += FBLK) X[i] = make_float2(0.f, 0.f);
    __syncthreads();
    for (int j = tid; j < D0n; j += FBLK) {
        float v = x0[(size_t)b * D0n + j] * (float)(2 * s0[j] - 1);
        atomicAdd(&Xf[h0[j]], v);
    }
    __syncthreads();
    fft_stage<N2,8000,20,false>(X, tw);        __syncthreads();
    if (doW) { w_consume(wbf, wr, uid, 0); w_issue(wsrc, wr, uid, 1); }
    fft_stage<N2,400, 20,false>(X, tw + 7600); __syncthreads();
    if (doW) { w_consume(wbf, wr, uid, 1); w_issue(wsrc, wr, uid, 2); }
    fft_stage<N2,20,  20,false>(X, tw);        __syncthreads();

    // spill C0 (scrambled order) as bf16 pairs
    for (int p = tid; p < N2; p += FBLK) {
        float2 v = X[p];
        c0row[p] = (uint32_t)f2bf(v.x) | ((uint32_t)f2bf(v.y) << 16);
    }
    __syncthreads();   // spill LDS reads done before zeroing
    if (doW) { w_consume(wbf, wr, uid, 2); w_issue(wsrc, wr, uid, 3); }

    // ---- FFT of c1 ----
    for (int i = tid; i < N2; i += FBLK) X[i] = make_float2(0.f, 0.f);
    __syncthreads();
    for (int j = tid; j < D1n; j += FBLK) {
        float v = x1[(size_t)b * D1n + j] * (float)(2 * s1[j] - 1);
        atomicAdd(&Xf[h1[j]], v);
    }
    __syncthreads();
    fft_stage<N2,8000,20,false>(X, tw);        __syncthreads();
    if (doW) { w_consume(wbf, wr, uid, 3); w_issue(wsrc, wr, uid, 4); }
    fft_stage<N2,400, 20,false>(X, tw + 7600); __syncthreads();
    if (doW) { w_consume(wbf, wr, uid, 4); w_issue(wsrc, wr, uid, 5); }
    fft_stage<N2,20,  20,false>(X, tw);        __syncthreads();
    // (barrier drained vmcnt -> C0 spill visible in L2 for read-back)

    // ---- untangle + multiply + retangle (pairs k, 8000-k) ----
    // t-mapping puts consecutive lanes at consecutive pa (bank-friendly)
    for (int t = tid; t <= 4000; t += FBLK) {
        int k;
        if (t == 4000) k = 4000;
        else { int d2 = t % 10, r = t / 10; k = (r / 20) + 20 * (r % 20) + 400 * d2; }
        int kb = (k == 0) ? 0 : (N2 - k);
        int pa = sigma_inv8k(k), pb = sigma_inv8k(kb);
        float2 C1a = X[pa], C1b = X[pb];
        float2 C0a = bf2c(c0row[pa]), C0b = bf2c(c0row[pb]);
        float2 E0 = make_float2(0.5f * (C0a.x + C0b.x), 0.5f * (C0a.y - C0b.y));
        float2 dv0 = make_float2(C0a.x - C0b.x, C0a.y + C0b.y);
        float2 O0 = make_float2(0.5f * dv0.y, -0.5f * dv0.x);
        float2 E1 = make_float2(0.5f * (C1a.x + C1b.x), 0.5f * (C1a.y - C1b.y));
        float2 dv1 = make_float2(C1a.x - C1b.x, C1a.y + C1b.y);
        float2 O1 = make_float2(0.5f * dv1.y, -0.5f * dv1.x);
        float2 Wq = utw[k];
        float2 Ez = cmul(E0, E1) + cmul(Wq, cmul(O0, O1));
        float2 Oz = cmul(E0, O1) + cmul(O0, E1);
        X[pa] = make_float2(Ez.x - Oz.y, Ez.y + Oz.x);       // D[k]
        X[pb] = make_float2(Ez.x + Oz.y, Oz.x - Ez.y);       // D[8000-k]
    }
    __syncthreads();
    if (doW) w_consume(wbf, wr, uid, 5);

    // ---- inverse FFT ----
    fft_stage<N2,20,  20,true>(X, tw);        __syncthreads();
    fft_stage<N2,400, 20,true>(X, tw + 7600); __syncthreads();
    fft_stage<N2,8000,20,true>(X, tw);        __syncthreads();

    const float invN = 1.0f / (float)N2;
    uint32_t* zrow = (uint32_t*)(zb + (size_t)b * MMn);
    for (int n = tid; n < N2; n += FBLK) {
        float2 v = X[n];
        zrow[n] = (uint32_t)f2bf(v.x * invN) | ((uint32_t)f2bf(v.y * invN) << 16);
    }
}

// ---------------------------------------------------------------------------
// Split-K GEMM: partial[s] = Z[:, ks:ke] @ Wb[:, ks:ke]^T  (validated R3/R4)
// ---------------------------------------------------------------------------
#define PCOLS 3072
#define PSTRIDE ((size_t)Bsz * PCOLS)

__global__ __launch_bounds__(256, 3) void gemm_sk_kernel(
    const unsigned short* __restrict__ Z,    // [1024,16000] bf16
    const unsigned short* __restrict__ Wb,   // [3000,16000] bf16
    float* __restrict__ part)                // [4][1024][3072] f32
{
    __shared__ __align__(16) unsigned char As[16384];
    __shared__ __align__(16) unsigned char Bs[16384];

    const int tid = threadIdx.x;
    const int n0 = blockIdx.x * 128;
    const int m0 = blockIdx.y * 128;
    const int sp = blockIdx.z;
    const int lane = tid & 63;
    const int w = tid >> 6, wm = w >> 1, wn = w & 1;
    const int lr = lane & 15, qh = lane >> 4;

    const unsigned char* aSrc[4]; const unsigned char* bSrc[4];
    int aLds[4], bLds[4];
#pragma unroll
    for (int i = 0; i < 4; i++) {
        int slot = i * 256 + tid;
        int r = slot >> 3, qp = slot & 7;
        int q = qp ^ (r & 7);
        aSrc[i] = (const unsigned char*)(Z + (size_t)(m0 + r) * MMn + q * 8);
        aLds[i] = slot * 16;
        int rw = n0 + r; if (rw > OUTn - 1) rw = OUTn - 1;
        bSrc[i] = (const unsigned char*)(Wb + (size_t)rw * MMn + q * 8);
        bLds[i] = slot * 16;
    }

    int aOff[4], bOff[4];
#pragma unroll
    for (int i = 0; i < 4; i++) {
        aOff[i] = (wm * 64 + i * 16 + lr) * 128 + ((qh ^ (lr & 7)) * 16);
        bOff[i] = (wn * 64 + i * 16 + lr) * 128 + ((qh ^ (lr & 7)) * 16);
    }

    f32x4 acc[4][4];
#pragma unroll
    for (int i = 0; i < 4; i++)
#pragma unroll
        for (int j = 0; j < 4; j++)
            acc[i][j] = (f32x4){0.f, 0.f, 0.f, 0.f};

    const int it_b = (250 * sp) / 4, it_e = (250 * (sp + 1)) / 4;
    for (int it = it_b; it < it_e; ++it) {
        const size_t koff = (size_t)it * 128;
        __syncthreads();
#pragma unroll
        for (int i = 0; i < 4; i++) {
            gll16(aSrc[i] + koff, As + aLds[i]);
            gll16(bSrc[i] + koff, Bs + bLds[i]);
        }
        __syncthreads();
#pragma unroll
        for (int kk = 0; kk < 2; kk++) {
            const int kx = kk << 6;
            bf16x8 af[4], bfv[4];
#pragma unroll
            for (int i = 0; i < 4; i++) af[i]  = *(const bf16x8*)(As + (aOff[i] ^ kx));
#pragma unroll
            for (int j = 0; j < 4; j++) bfv[j] = *(const bf16x8*)(Bs + (bOff[j] ^ kx));
#pragma unroll
            for (int i = 0; i < 4; i++)
#pragma unroll
                for (int j = 0; j < 4; j++)
                    acc[i][j] = __builtin_amdgcn_mfma_f32_16x16x32_bf16(
                        af[i], bfv[j], acc[i][j], 0, 0, 0);
        }
    }

    float* pdst = part + (size_t)sp * PSTRIDE;
#pragma unroll
    for (int j = 0; j < 4; j++) {
        int n = n0 + wn * 64 + j * 16 + lr;
#pragma unroll
        for (int i = 0; i < 4; i++) {
            int mb = m0 + wm * 64 + i * 16 + qh * 4;
#pragma unroll
            for (int reg = 0; reg < 4; reg++)
                pdst[(size_t)(mb + reg) * PCOLS + n] = acc[i][j][reg];
        }
    }
}

// out = relu(sum_s part[s] + bias)
__global__ __launch_bounds__(256) void reduce_kernel(
    const float* __restrict__ part, const float* __restrict__ bias,
    float* __restrict__ out)
{
    int idx = blockIdx.x * 256 + threadIdx.x;
    int b = idx / 750, oq = idx - b * 750;
    int o = oq * 4;
    const float* p = part + (size_t)b * PCOLS + o;
    float4 s0 = *(const float4*)(p);
    float4 s1 = *(const float4*)(p + PSTRIDE);
    float4 s2 = *(const float4*)(p + 2 * PSTRIDE);
    float4 s3 = *(const float4*)(p + 3 * PSTRIDE);
    float4 bv = *(const float4*)(bias + o);
    float4 r;
    r.x = s0.x + s1.x + s2.x + s3.x + bv.x; r.x = r.x > 0.f ? r.x : 0.f;
    r.y = s0.y + s1.y + s2.y + s3.y + bv.y; r.y = r.y > 0.f ? r.y : 0.f;
    r.z = s0.z + s1.z + s2.z + s3.z + bv.z; r.z = r.z > 0.f ? r.z : 0.f;
    r.w = s0.w + s1.w + s2.w + s3.w + bv.w; r.w = r.w > 0.f ? r.w : 0.f;
    *(float4*)(out + (size_t)b * OUTn + o) = r;
}

// ---------------------------------------------------------------------------
// Fallback GEMM (R2, validated): direct out, W f32 converted in-loop.
// ---------------------------------------------------------------------------
#define BM 64
#define BN 128
#define BK 32
#define LDK 40

__global__ __launch_bounds__(256) void gemm_kernel(
    const unsigned short* __restrict__ Z, const float* __restrict__ W,
    const float* __restrict__ bias, float* __restrict__ out)
{
    __shared__ __align__(16) unsigned short As2[BM * LDK];
    __shared__ __align__(16) unsigned short Bs2[BN * LDK];

    const int tid = threadIdx.x;
    const int m0 = blockIdx.y * BM;
    const int n0 = blockIdx.x * BN;
    const int lane = tid & 63;
    const int w  = tid >> 6;
    const int wm = w >> 1;
    const int wn = w & 1;

    const int ar = tid >> 2, aq = tid & 3;
    const uint4* aSrc = (const uint4*)(Z + (size_t)(m0 + ar) * MMn + aq * 8);
    unsigned short* aDst = As2 + ar * LDK + aq * 8;

    const float4* bSrc[4];
    unsigned short* bDst[4];
#pragma unroll
    for (int p = 0; p < 4; p++) {
        int ch = tid + 256 * p;
        int r = ch >> 3, q = ch & 7;
        int rw = n0 + r; if (rw > OUTn - 1) rw = OUTn - 1;
        bSrc[p] = (const float4*)(W + (size_t)rw * MMn + q * 4);
        bDst[p] = Bs2 + r * LDK + q * 4;
    }

    const int qh = lane >> 4;
    const int lr = lane & 15;
    const unsigned short* aRd[2];
    const unsigned short* bRd[4];
#pragma unroll
    for (int i = 0; i < 2; i++) aRd[i] = As2 + (wm * 32 + i * 16 + lr) * LDK + qh * 8;
#pragma unroll
    for (int j = 0; j < 4; j++) bRd[j] = Bs2 + (wn * 64 + j * 16 + lr) * LDK + qh * 8;

    f32x4 acc[2][4];
#pragma unroll
    for (int i = 0; i < 2; i++)
#pragma unroll
        for (int j = 0; j < 4; j++)
            acc[i][j] = (f32x4){0.f, 0.f, 0.f, 0.f};

    for (int k0 = 0; k0 < MMn; k0 += BK) {
        uint4 av = aSrc[k0 >> 3];
        float4 bv[4];
#pragma unroll
        for (int p = 0; p < 4; p++) bv[p] = bSrc[p][k0 >> 2];

        __syncthreads();
        *(uint4*)aDst = av;
#pragma unroll
        for (int p = 0; p < 4; p++) {
            uint2 pk;
            pk.x = (uint32_t)f2bf(bv[p].x) | ((uint32_t)f2bf(bv[p].y) << 16);
            pk.y = (uint32_t)f2bf(bv[p].z) | ((uint32_t)f2bf(bv[p].w) << 16);
            *(uint2*)bDst[p] = pk;
        }
        __syncthreads();

        bf16x8 af[2], bfr[4];
#pragma unroll
        for (int i = 0; i < 2; i++) af[i] = *(const bf16x8*)aRd[i];
#pragma unroll
        for (int j = 0; j < 4; j++) bfr[j] = *(const bf16x8*)bRd[j];
#pragma unroll
        for (int i = 0; i < 2; i++)
#pragma unroll
            for (int j = 0; j < 4; j++)
                acc[i][j] = __builtin_amdgcn_mfma_f32_16x16x32_bf16(
                    af[i], bfr[j], acc[i][j], 0, 0, 0);
    }

#pragma unroll
    for (int j = 0; j < 4; j++) {
        int n = n0 + wn * 64 + j * 16 + lr;
        if (n < OUTn) {
            float bvb = bias[n];
#pragma unroll
            for (int i = 0; i < 2; i++) {
                int mb = m0 + wm * 32 + i * 16 + qh * 4;
#pragma unroll
                for (int reg = 0; reg < 4; reg++) {
                    float v = acc[i][j][reg] + bvb;
                    out[(size_t)(mb + reg) * OUTn + n] = v > 0.f ? v : 0.f;
                }
            }
        }
    }
}

// ---------------------------------------------------------------------------
// ws layout (full path; NEED identical to R4's proven 179,227,648):
//   [0, 32768000)              zb   bf16 [1024][16000]
//   [32768000, 32864000)       tw   float2 [11981] (+pad to 32896000)
//   [32896000, 128896000)      Wbf  bf16 [3000][16000]
//   [128896000, 179227648)     part f32 [4][1024][3072]  (c0 spill aliases
//                              the first 32.77 MB — disjoint lifetimes)
// ---------------------------------------------------------------------------
extern "C" void kernel_launch(void* const* d_in, const int* in_sizes, int n_in,
                              void* d_out, int out_size, void* d_ws, size_t ws_size,
                              hipStream_t stream) {
    const float* x0 = (const float*)d_in[0];
    const float* x1 = (const float*)d_in[1];
    const int*   h0 = (const int*)d_in[2];
    const int*   h1 = (const int*)d_in[3];
    const int*   s0 = (const int*)d_in[4];
    const int*   s1 = (const int*)d_in[5];
    const float* W  = (const float*)d_in[6];
    const float* bb = (const float*)d_in[7];
    float* out = (float*)d_out;

    unsigned char* ws = (unsigned char*)d_ws;
    unsigned short* zb  = (unsigned short*)(ws);
    float2*         tw  = (float2*)(ws + 32768000);
    unsigned short* wbf = (unsigned short*)(ws + 32896000);
    float*          prt = (float*)(ws + 128896000);
    const size_t NEED = 128896000 + 4 * PSTRIDE * sizeof(float);
    const int doW = (ws_size >= NEED) ? 1 : 0;
    // c0 spill: aliases part region (full path) or wbf region (fallback path)
    uint32_t* c0g = doW ? (uint32_t*)(ws + 128896000) : (uint32_t*)(ws + 32896000);

    tw_init_kernel<<<(TWN + 255) / 256, 256, 0, stream>>>(tw);
    fft_conv_kernel<<<Bsz, FBLK, 0, stream>>>(x0, x1, h0, h1, s0, s1, tw,
                                              W, wbf, doW, c0g, zb);

    if (doW) {
        dim3 g((OUTn + 127) / 128, Bsz / 128, 4);
        gemm_sk_kernel<<<g, 256, 0, stream>>>(zb, wbf, prt);
        reduce_kernel<<<Bsz * (OUTn / 4) / 256, 256, 0, stream>>>(prt, bb, out);
    } else {
        dim3 g((OUTn + BN - 1) / BN, Bsz / BM);
        gemm_kernel<<<g, 256, 0, stream>>>(zb, W, bb, out);
    }
}